// Round 5
// baseline (903.927 us; speedup 1.0000x reference)
//
#include <hip/hip_runtime.h>
#include <math.h>

#define NNODES 10000
#define NEDGES 160000
#define E2 (NEDGES + NNODES)
#define F_IN 50
#define HIDC 350
#define NH1 4
#define NH2 4
#define NH3 6
#define OUTC 121
#define MAXE 512
#define KP1 64      // F_IN=50 padded to 64
#define KP2 1408    // 1400 padded to 1408
#define ROWSLACK 128

typedef __attribute__((ext_vector_type(8))) short short8;
typedef __attribute__((ext_vector_type(4))) float floatx4;

static __device__ __forceinline__ unsigned short f2bf(float f) {
    unsigned u = __float_as_uint(f);
    unsigned r = (u + 0x7fffu + ((u >> 16) & 1u)) >> 16;
    return (unsigned short)r;
}
static __device__ __forceinline__ float bf2f(unsigned short s) {
    return __uint_as_float(((unsigned)s) << 16);
}

// async global->LDS, 16 bytes per lane; LDS dest is wave-uniform base + lane*16
#define GLL16(gp, lp)                                                      \
    __builtin_amdgcn_global_load_lds(                                      \
        (const __attribute__((address_space(1))) void*)(gp),               \
        (__attribute__((address_space(3))) void*)(lp), 16, 0, 0)

// ---------------- CSR build (dst-sorted incoming edge lists) ----------------
__global__ void count_kernel(const int* __restrict__ ei, int* __restrict__ cnt) {
    int i = blockIdx.x * blockDim.x + threadIdx.x;
    if (i >= E2) return;
    int dst = (i < NEDGES) ? ei[NEDGES + i] : (i - NEDGES);
    atomicAdd(&cnt[dst], 1);
}

// exclusive scan; writes both indptr and cursor
__global__ void scan_kernel(const int* __restrict__ cnt, int* __restrict__ indptr,
                            int* __restrict__ cursor) {
    __shared__ int part[1024];
    int tid = threadIdx.x;
    const int CH = (NNODES + 1023) / 1024;
    int base = tid * CH;
    int s = 0;
    for (int i = 0; i < CH; i++) {
        int idx = base + i;
        if (idx < NNODES) s += cnt[idx];
    }
    part[tid] = s;
    __syncthreads();
    for (int off = 1; off < 1024; off <<= 1) {
        int v = (tid >= off) ? part[tid - off] : 0;
        __syncthreads();
        part[tid] += v;
        __syncthreads();
    }
    int run = (tid == 0) ? 0 : part[tid - 1];
    for (int i = 0; i < CH; i++) {
        int idx = base + i;
        if (idx < NNODES) {
            indptr[idx] = run;
            cursor[idx] = run;
            run += cnt[idx];
        }
    }
    if (tid == 0) indptr[NNODES] = part[1023];
}

__global__ void scatter_kernel(const int* __restrict__ ei, int* __restrict__ cursor,
                               int* __restrict__ esrc) {
    int i = blockIdx.x * blockDim.x + threadIdx.x;
    if (i >= E2) return;
    int src, dst;
    if (i < NEDGES) {
        src = ei[i];
        dst = ei[NEDGES + i];
    } else {
        src = dst = i - NEDGES;
    }
    int pos = atomicAdd(&cursor[dst], 1);
    esrc[pos] = src;
}

// ---------------- fused fp32 -> bf16 hi/lo splits ----------------
__global__ void splitA_kernel(const float* __restrict__ x, const float* __restrict__ W1,
                              unsigned short* __restrict__ xHi, unsigned short* __restrict__ xLo,
                              unsigned short* __restrict__ w1Hi, unsigned short* __restrict__ w1Lo) {
    int k = threadIdx.x;  // 0..63
    int r = blockIdx.y;
    const float* src;
    unsigned short *hi, *lo;
    int row;
    if (r < NNODES) { src = x; row = r; hi = xHi; lo = xLo; }
    else { src = W1; row = r - NNODES; hi = w1Hi; lo = w1Lo; }
    float v = (k < F_IN) ? src[(size_t)row * F_IN + k] : 0.f;
    unsigned short h = f2bf(v);
    hi[(size_t)row * KP1 + k] = h;
    lo[(size_t)row * KP1 + k] = f2bf(v - bf2f(h));
}

__global__ void splitB_kernel(const float* __restrict__ W2, const float* __restrict__ Wsk,
                              const float* __restrict__ W3,
                              unsigned short* __restrict__ w2Hi, unsigned short* __restrict__ w2Lo,
                              unsigned short* __restrict__ w3Hi, unsigned short* __restrict__ w3Lo) {
    int k = blockIdx.x * blockDim.x + threadIdx.x;
    if (k >= KP2) return;
    int r = blockIdx.y;
    const int K = 1400;
    const float* src;
    unsigned short *hi, *lo;
    int row;
    if (r < 1400) { src = W2; row = r; hi = w2Hi; lo = w2Lo; }
    else if (r < 2800) { src = Wsk; row = r - 1400; hi = w2Hi + (size_t)1400 * KP2; lo = w2Lo + (size_t)1400 * KP2; }
    else { src = W3; row = r - 2800; hi = w3Hi; lo = w3Lo; }
    float v = (k < K) ? src[(size_t)row * K + k] : 0.f;
    unsigned short h = f2bf(v);
    hi[(size_t)row * KP2 + k] = h;
    lo[(size_t)row * KP2 + k] = f2bf(v - bf2f(h));
}

// ---------------- a-tilde precompute: at[h][k] = sum_c W[h*C+c, k] * a[h,c] ----
// out buffers must be pre-zeroed (atomic accumulation over c-chunks).
__global__ void atil_kernel(const float* __restrict__ W, const float* __restrict__ av_s,
                            const float* __restrict__ av_d, float* __restrict__ outS,
                            float* __restrict__ outD, int C, int K, int cchunk) {
    int k = blockIdx.x * 64 + (threadIdx.x & 63);
    if (k >= K) return;
    int h = blockIdx.y;
    int c0 = blockIdx.z * cchunk;
    int c1 = c0 + cchunk;
    if (c1 > C) c1 = C;
    float ss = 0.f, dd = 0.f;
    for (int c = c0; c < c1; c++) {
        float wv = W[((size_t)h * C + c) * K + k];
        ss = fmaf(wv, av_s[h * C + c], ss);
        dd = fmaf(wv, av_d[h * C + c], dd);
    }
    atomicAdd(&outS[(size_t)h * K + k], ss);
    atomicAdd(&outD[(size_t)h * K + k], dd);
}

// ---------------- layer-1 alpha directly from x: alpha[n,h] = x[n,:].at1[h,:] --
__global__ __launch_bounds__(256) void alpha1x_kernel(const float* __restrict__ x,
                                                      const float* __restrict__ at1s,
                                                      const float* __restrict__ at1d,
                                                      float* __restrict__ as1,
                                                      float* __restrict__ ad1) {
    int wave = threadIdx.x >> 6, lane = threadIdx.x & 63;
    int n = blockIdx.x * 4 + wave;
    if (n >= NNODES) return;
    int kk = lane < F_IN ? lane : F_IN - 1;
    float v = (lane < F_IN) ? x[(size_t)n * F_IN + lane] : 0.f;
    float p[8];
#pragma unroll
    for (int h = 0; h < 4; h++) {
        p[h] = v * at1s[h * F_IN + kk];
        p[4 + h] = v * at1d[h * F_IN + kk];
    }
#pragma unroll
    for (int s = 0; s < 8; s++)
#pragma unroll
        for (int o = 32; o > 0; o >>= 1) p[s] += __shfl_xor(p[s], o, 64);
    if (lane == 0) {
#pragma unroll
        for (int h = 0; h < 4; h++) {
            as1[n * 4 + h] = p[h];
            ad1[n * 4 + h] = p[4 + h];
        }
    }
}

// ---------------- split-bf16 MFMA GEMM, 128x256 tile ----------------
__global__ __launch_bounds__(256, 2) void gemm_hilo(
    const unsigned short* __restrict__ Ahi, const unsigned short* __restrict__ Alo,
    const unsigned short* __restrict__ Bhi, const unsigned short* __restrict__ Blo,
    float* __restrict__ C, int NN, int M, int Kp, int ldc) {
    __shared__ __align__(16) unsigned short sA[2][128 * 32];
    __shared__ __align__(16) unsigned short sB[2][256 * 32];
    int tid = threadIdx.x;
    int wave = tid >> 6, lane = tid & 63;
    int wm = (wave >> 1) * 64, wn = (wave & 1) * 128;
    int fr = lane & 15, kq = lane >> 4;
    int row0 = blockIdx.y * 128, col0 = blockIdx.x * 256;

    floatx4 acc[4][8];
#pragma unroll
    for (int i = 0; i < 4; i++)
#pragma unroll
        for (int j = 0; j < 8; j++)
#pragma unroll
            for (int q = 0; q < 4; q++) acc[i][j][q] = 0.f;

    int gpos = lane & 3;
    int rl = lane >> 2;
    int gsw = kq ^ ((fr >> 1) & 3);

    for (int k0 = 0; k0 < Kp; k0 += 32) {
#pragma unroll
        for (int c = 0; c < 2; ++c) {
            int r = wave * 32 + c * 16 + rl;
            int g = gpos ^ ((r >> 1) & 3);
            size_t gofs = (size_t)(row0 + r) * Kp + k0 + g * 8;
            size_t lofs = (size_t)r * 32 + (size_t)gpos * 8;
            GLL16(Ahi + gofs, &sA[0][lofs]);
            GLL16(Alo + gofs, &sA[1][lofs]);
        }
#pragma unroll
        for (int c = 0; c < 4; ++c) {
            int r = wave * 64 + c * 16 + rl;
            int g = gpos ^ ((r >> 1) & 3);
            size_t gofs = (size_t)(col0 + r) * Kp + k0 + g * 8;
            size_t lofs = (size_t)r * 32 + (size_t)gpos * 8;
            GLL16(Bhi + gofs, &sB[0][lofs]);
            GLL16(Blo + gofs, &sB[1][lofs]);
        }
        __syncthreads();

        short8 ah[4], al[4], bh[8], bl[8];
#pragma unroll
        for (int j = 0; j < 8; j++) {
            int rb = wn + j * 16 + fr;
            bh[j] = *(const short8*)&sB[0][rb * 32 + gsw * 8];
            bl[j] = *(const short8*)&sB[1][rb * 32 + gsw * 8];
        }
#pragma unroll
        for (int i = 0; i < 4; i++) {
            int ra = wm + i * 16 + fr;
            ah[i] = *(const short8*)&sA[0][ra * 32 + gsw * 8];
            al[i] = *(const short8*)&sA[1][ra * 32 + gsw * 8];
        }
#pragma unroll
        for (int i = 0; i < 4; i++)
#pragma unroll
            for (int j = 0; j < 8; j++) {
                acc[i][j] = __builtin_amdgcn_mfma_f32_16x16x32_bf16(ah[i], bh[j],
                                                                   acc[i][j], 0, 0, 0);
                acc[i][j] = __builtin_amdgcn_mfma_f32_16x16x32_bf16(al[i], bh[j],
                                                                   acc[i][j], 0, 0, 0);
                acc[i][j] = __builtin_amdgcn_mfma_f32_16x16x32_bf16(ah[i], bl[j],
                                                                   acc[i][j], 0, 0, 0);
            }
        __syncthreads();
    }

    // C/D layout: col=lane&15, row=(lane>>4)*4+reg
#pragma unroll
    for (int i = 0; i < 4; i++) {
#pragma unroll
        for (int rg = 0; rg < 4; rg++) {
            int rr = row0 + wm + i * 16 + kq * 4 + rg;
            if (rr >= NN) continue;
#pragma unroll
            for (int j = 0; j < 8; j++) {
                int cc = col0 + wn + j * 16 + fr;
                if (cc < M) C[(size_t)rr * ldc + cc] = acc[i][j][rg];
            }
        }
    }
}

// ---------------- softmax-weighted aggregation, one block per dst node -------
// MODE 0: act = agg + bias (+ELU) (+skip); emit bf16 hi/lo; if HN>0 also
//         compute next-layer alpha: asx/adx[n,h] = act . atns/atnd[h,:]
// MODE 1: outF[n, C] = mean_heads(agg) + bias (fp32)
#define AGG_T 384
template <int H, int C, int MODE, int DOELU, int SKIP, int HN>
__global__ __launch_bounds__(AGG_T) void agg2(
    const float* __restrict__ hpre, int ldh, const float* __restrict__ skip,
    const float* __restrict__ as_n, const float* __restrict__ ad_n,
    const int* __restrict__ indptr, const int* __restrict__ esrc,
    const float* __restrict__ bias, unsigned short* __restrict__ outHi,
    unsigned short* __restrict__ outLo, int Kp, float* __restrict__ outF,
    const float* __restrict__ atns, const float* __restrict__ atnd,
    float* __restrict__ asx, float* __restrict__ adx) {
    constexpr int HC = H * C;
    int n = blockIdx.x;
    int tid = threadIdx.x;
    int s = indptr[n], e = indptr[n + 1];
    int deg = e - s;
    if (deg > MAXE) deg = MAXE;

    __shared__ int srcs[MAXE];
    __shared__ float wgt[MAXE * H];
    __shared__ float aggsh[MODE ? HC : 1];
    __shared__ float sAl[16];
    if (tid < 16) sAl[tid] = 0.f;

    // ---- phase 1: softmax weights, wave 0 only ----
    if (tid < 64) {
        int lane = tid;
        float adv[H], mx[H], sm[H];
#pragma unroll
        for (int h = 0; h < H; h++) {
            adv[h] = ad_n[n * H + h];
            mx[h] = -1e30f;
            sm[h] = 0.f;
        }
        for (int j = lane; j < deg; j += 64) {
            int sr = esrc[s + j];
            srcs[j] = sr;
#pragma unroll
            for (int h = 0; h < H; h++) {
                float ev = as_n[sr * H + h] + adv[h];
                ev = ev > 0.f ? ev : 0.2f * ev;
                wgt[j * H + h] = ev;
                mx[h] = fmaxf(mx[h], ev);
            }
        }
#pragma unroll
        for (int h = 0; h < H; h++)
#pragma unroll
            for (int o = 32; o > 0; o >>= 1) mx[h] = fmaxf(mx[h], __shfl_xor(mx[h], o, 64));
        for (int j = lane; j < deg; j += 64) {
#pragma unroll
            for (int h = 0; h < H; h++) {
                float p = __expf(wgt[j * H + h] - mx[h]);
                wgt[j * H + h] = p;
                sm[h] += p;
            }
        }
#pragma unroll
        for (int h = 0; h < H; h++) {
#pragma unroll
            for (int o = 32; o > 0; o >>= 1) sm[h] += __shfl_xor(sm[h], o, 64);
            sm[h] = 1.f / sm[h];
        }
        for (int j = lane; j < deg; j += 64) {
#pragma unroll
            for (int h = 0; h < H; h++) wgt[j * H + h] *= sm[h];
        }
    }
    __syncthreads();

    // ---- phase 2: weighted gather over channels ----
    if (MODE == 0) {
        constexpr int NV4 = HC / 4;
        constexpr int NP = (HN > 0) ? 2 * HN : 1;
        float p[NP];
#pragma unroll
        for (int q = 0; q < NP; q++) p[q] = 0.f;

        for (int c4 = tid; c4 < NV4; c4 += AGG_T) {
            int cb = c4 * 4;
            int h0 = (cb + 0) / C, h1 = (cb + 1) / C;
            int h2c = (cb + 2) / C, h3 = (cb + 3) / C;
            float ax = 0.f, ay = 0.f, az = 0.f, aw = 0.f;
            int j = 0;
            for (; j + 3 < deg; j += 4) {
                const float4 v0 = *(const float4*)(hpre + (size_t)srcs[j] * ldh + cb);
                const float4 v1 = *(const float4*)(hpre + (size_t)srcs[j + 1] * ldh + cb);
                const float4 v2 = *(const float4*)(hpre + (size_t)srcs[j + 2] * ldh + cb);
                const float4 v3 = *(const float4*)(hpre + (size_t)srcs[j + 3] * ldh + cb);
                const float* w0 = &wgt[j * H];
                const float* w1 = &wgt[(j + 1) * H];
                const float* w2 = &wgt[(j + 2) * H];
                const float* w3 = &wgt[(j + 3) * H];
                ax = fmaf(w0[h0], v0.x, ax); ay = fmaf(w0[h1], v0.y, ay);
                az = fmaf(w0[h2c], v0.z, az); aw = fmaf(w0[h3], v0.w, aw);
                ax = fmaf(w1[h0], v1.x, ax); ay = fmaf(w1[h1], v1.y, ay);
                az = fmaf(w1[h2c], v1.z, az); aw = fmaf(w1[h3], v1.w, aw);
                ax = fmaf(w2[h0], v2.x, ax); ay = fmaf(w2[h1], v2.y, ay);
                az = fmaf(w2[h2c], v2.z, az); aw = fmaf(w2[h3], v2.w, aw);
                ax = fmaf(w3[h0], v3.x, ax); ay = fmaf(w3[h1], v3.y, ay);
                az = fmaf(w3[h2c], v3.z, az); aw = fmaf(w3[h3], v3.w, aw);
            }
            for (; j < deg; j++) {
                const float4 v0 = *(const float4*)(hpre + (size_t)srcs[j] * ldh + cb);
                const float* w0 = &wgt[j * H];
                ax = fmaf(w0[h0], v0.x, ax); ay = fmaf(w0[h1], v0.y, ay);
                az = fmaf(w0[h2c], v0.z, az); aw = fmaf(w0[h3], v0.w, aw);
            }
            ax += bias[cb + 0];
            ay += bias[cb + 1];
            az += bias[cb + 2];
            aw += bias[cb + 3];
            if (DOELU) {
                ax = ax > 0.f ? ax : expm1f(ax);
                ay = ay > 0.f ? ay : expm1f(ay);
                az = az > 0.f ? az : expm1f(az);
                aw = aw > 0.f ? aw : expm1f(aw);
            }
            if (SKIP) {
                const float4 sk = *(const float4*)(skip + (size_t)n * ldh + cb);
                ax += sk.x;
                ay += sk.y;
                az += sk.z;
                aw += sk.w;
            }
            if (HN > 0) {
                float vq[4] = {ax, ay, az, aw};
#pragma unroll
                for (int h = 0; h < HN; h++) {
                    float ss = 0.f, dd = 0.f;
#pragma unroll
                    for (int q = 0; q < 4; q++) {
                        ss = fmaf(vq[q], atns[(size_t)h * HC + cb + q], ss);
                        dd = fmaf(vq[q], atnd[(size_t)h * HC + cb + q], dd);
                    }
                    p[h] += ss;
                    p[HN + h] += dd;
                }
            }
            ushort4 hi4, lo4;
            hi4.x = f2bf(ax); lo4.x = f2bf(ax - bf2f(hi4.x));
            hi4.y = f2bf(ay); lo4.y = f2bf(ay - bf2f(hi4.y));
            hi4.z = f2bf(az); lo4.z = f2bf(az - bf2f(hi4.z));
            hi4.w = f2bf(aw); lo4.w = f2bf(aw - bf2f(hi4.w));
            *(ushort4*)(outHi + (size_t)n * Kp + cb) = hi4;
            *(ushort4*)(outLo + (size_t)n * Kp + cb) = lo4;
        }
        for (int c = HC + tid; c < Kp; c += AGG_T) {
            outHi[(size_t)n * Kp + c] = 0;
            outLo[(size_t)n * Kp + c] = 0;
        }
        if (HN > 0) {
#pragma unroll
            for (int q = 0; q < NP; q++)
#pragma unroll
                for (int o = 32; o > 0; o >>= 1) p[q] += __shfl_xor(p[q], o, 64);
            if ((tid & 63) == 0) {
#pragma unroll
                for (int q = 0; q < NP; q++) atomicAdd(&sAl[q], p[q]);
            }
            __syncthreads();
            if (tid < HN) asx[n * HN + tid] = sAl[tid];
            else if (tid < 2 * HN) adx[n * HN + (tid - HN)] = sAl[tid];
        }
    } else {
        for (int cc = tid; cc < HC; cc += AGG_T) {
            int h = cc / C;
            float a = 0.f;
            for (int j = 0; j < deg; ++j)
                a = fmaf(wgt[j * H + h], hpre[(size_t)srcs[j] * ldh + cc], a);
            aggsh[cc] = a;
        }
        __syncthreads();
        for (int c = tid; c < C; c += AGG_T) {
            float sres = 0.f;
#pragma unroll
            for (int h = 0; h < H; h++) sres += aggsh[h * C + c];
            outF[(size_t)n * C + c] = sres * (1.f / (float)H) + bias[c];
        }
    }
}

// ---------------- launcher ----------------
extern "C" void kernel_launch(void* const* d_in, const int* in_sizes, int n_in,
                              void* d_out, int out_size, void* d_ws, size_t ws_size,
                              hipStream_t stream) {
    const float* x = (const float*)d_in[0];
    const int* ei = (const int*)d_in[1];
    const float* W1 = (const float*)d_in[2];
    const float* a1s = (const float*)d_in[3];
    const float* a1d = (const float*)d_in[4];
    const float* b1 = (const float*)d_in[5];
    const float* W2 = (const float*)d_in[6];
    const float* a2s = (const float*)d_in[7];
    const float* a2d = (const float*)d_in[8];
    const float* b2 = (const float*)d_in[9];
    const float* Wsk = (const float*)d_in[10];
    const float* W3 = (const float*)d_in[11];
    const float* a3s = (const float*)d_in[12];
    const float* a3d = (const float*)d_in[13];
    const float* b3 = (const float*)d_in[14];
    float* out = (float*)d_out;

    char* w = (char*)d_ws;
    size_t off = 0;
    auto alloc = [&](size_t bytes) -> char* {
        char* p = w + off;
        off += (bytes + 255) & ~(size_t)255;
        return p;
    };
    float* hpre = (float*)alloc((size_t)NNODES * 2800 * 4);
    unsigned short* actHi = (unsigned short*)alloc((size_t)(NNODES + ROWSLACK) * KP2 * 2);
    unsigned short* actLo = (unsigned short*)alloc((size_t)(NNODES + ROWSLACK) * KP2 * 2);
    unsigned short* xHi = (unsigned short*)alloc((size_t)(NNODES + ROWSLACK) * KP1 * 2);
    unsigned short* xLo = (unsigned short*)alloc((size_t)(NNODES + ROWSLACK) * KP1 * 2);
    unsigned short* w1Hi = (unsigned short*)alloc((size_t)(1400 + ROWSLACK) * KP1 * 2);
    unsigned short* w1Lo = (unsigned short*)alloc((size_t)(1400 + ROWSLACK) * KP1 * 2);
    unsigned short* w2Hi = (unsigned short*)alloc((size_t)(2800 + ROWSLACK) * KP2 * 2);
    unsigned short* w2Lo = (unsigned short*)alloc((size_t)(2800 + ROWSLACK) * KP2 * 2);
    unsigned short* w3Hi = (unsigned short*)alloc((size_t)(726 + ROWSLACK) * KP2 * 2);
    unsigned short* w3Lo = (unsigned short*)alloc((size_t)(726 + ROWSLACK) * KP2 * 2);
    // a-tilde block: at1s(200) at1d(200) at2s(5600) at2d(5600) at3s(8400) at3d(8400)
    float* atall = (float*)alloc((size_t)28400 * 4);
    float* at1s = atall;
    float* at1d = atall + 200;
    float* at2s = atall + 400;
    float* at2d = atall + 6000;
    float* at3s = atall + 11600;
    float* at3d = atall + 20000;
    float* asP = (float*)alloc((size_t)NNODES * 6 * 4);
    float* adP = (float*)alloc((size_t)NNODES * 6 * 4);
    float* asQ = (float*)alloc((size_t)NNODES * 6 * 4);
    float* adQ = (float*)alloc((size_t)NNODES * 6 * 4);
    int* cnt = (int*)alloc((size_t)(NNODES + 16) * 4);
    int* indptr = (int*)alloc((size_t)(NNODES + 16) * 4);
    int* cursor = (int*)alloc((size_t)(NNODES + 16) * 4);
    int* esrc = (int*)alloc((size_t)E2 * 4);

    // ---- weight/input hi-lo splits + a-tilde precompute ----
    splitA_kernel<<<dim3(1, NNODES + 1400), 64, 0, stream>>>(x, W1, xHi, xLo, w1Hi, w1Lo);
    splitB_kernel<<<dim3(6, 2800 + 726), 256, 0, stream>>>(W2, Wsk, W3, w2Hi, w2Lo,
                                                           w3Hi, w3Lo);
    hipMemsetAsync(atall, 0, 28400 * 4, stream);
    atil_kernel<<<dim3(1, 4, 5), 64, 0, stream>>>(W1, a1s, a1d, at1s, at1d, HIDC, F_IN, 70);
    atil_kernel<<<dim3(22, 4, 5), 64, 0, stream>>>(W2, a2s, a2d, at2s, at2d, HIDC, 1400, 70);
    atil_kernel<<<dim3(22, 6, 4), 64, 0, stream>>>(W3, a3s, a3d, at3s, at3d, OUTC, 1400, 31);
    // layer-1 alpha straight from x
    alpha1x_kernel<<<(NNODES + 3) / 4, 256, 0, stream>>>(x, at1s, at1d, asP, adP);

    // ---- CSR build ----
    hipMemsetAsync(cnt, 0, NNODES * sizeof(int), stream);
    count_kernel<<<(E2 + 255) / 256, 256, 0, stream>>>(ei, cnt);
    scan_kernel<<<1, 1024, 0, stream>>>(cnt, indptr, cursor);
    scatter_kernel<<<(E2 + 255) / 256, 256, 0, stream>>>(ei, cursor, esrc);

    dim3 blk(256);
    int gy = (NNODES + 127) / 128;  // 79

    // ---- Layer 1 ----
    {
        int M = NH1 * HIDC;  // 1400
        dim3 grid((M + 255) / 256, gy);
        gemm_hilo<<<grid, blk, 0, stream>>>(xHi, xLo, w1Hi, w1Lo, hpre, NNODES, M, KP1, M);
        // agg reads alpha1 (P), writes act1 + alpha2 (Q)
        agg2<NH1, HIDC, 0, 1, 0, 4><<<NNODES, AGG_T, 0, stream>>>(
            hpre, M, nullptr, asP, adP, indptr, esrc, b1, actHi, actLo, KP2, nullptr,
            at2s, at2d, asQ, adQ);
    }
    // ---- Layer 2 (fused with skip: B = [W2; Wskip], M = 2800) ----
    {
        int HC = NH2 * HIDC;  // 1400
        int M = 2 * HC;       // 2800
        dim3 grid((M + 255) / 256, gy);
        gemm_hilo<<<grid, blk, 0, stream>>>(actHi, actLo, w2Hi, w2Lo, hpre, NNODES, M, KP2, M);
        // agg reads alpha2 (Q), writes act2 + alpha3 (P)
        agg2<NH2, HIDC, 0, 1, 1, 6><<<NNODES, AGG_T, 0, stream>>>(
            hpre, M, hpre + HC, asQ, adQ, indptr, esrc, b2, actHi, actLo, KP2, nullptr,
            at3s, at3d, asP, adP);
    }
    // ---- Layer 3 ----
    {
        int M = NH3 * OUTC;  // 726
        dim3 grid((M + 255) / 256, gy);
        gemm_hilo<<<grid, blk, 0, stream>>>(actHi, actLo, w3Hi, w3Lo, hpre, NNODES, M, KP2, M);
        agg2<NH3, OUTC, 1, 0, 0, 0><<<NNODES, AGG_T, 0, stream>>>(
            hpre, M, nullptr, asP, adP, indptr, esrc, b3, nullptr, nullptr, 0, out,
            nullptr, nullptr, nullptr, nullptr);
    }
}

// Round 6
// 884.486 us; speedup vs baseline: 1.0220x; 1.0220x over previous
//
#include <hip/hip_runtime.h>
#include <math.h>

#define NNODES 10000
#define NEDGES 160000
#define E2 (NEDGES + NNODES)
#define F_IN 50
#define HIDC 350
#define NH1 4
#define NH2 4
#define NH3 6
#define OUTC 121
#define MAXE 512
#define KP1 64      // F_IN=50 padded to 64
#define KP2 1408    // 1400 padded to 1408
#define ROWSLACK 128

typedef __attribute__((ext_vector_type(8))) short short8;
typedef __attribute__((ext_vector_type(4))) float floatx4;

static __device__ __forceinline__ unsigned short f2bf(float f) {
    unsigned u = __float_as_uint(f);
    unsigned r = (u + 0x7fffu + ((u >> 16) & 1u)) >> 16;
    return (unsigned short)r;
}
static __device__ __forceinline__ float bf2f(unsigned short s) {
    return __uint_as_float(((unsigned)s) << 16);
}

// async global->LDS, 16 bytes per lane; LDS dest is wave-uniform base + lane*16
#define GLL16(gp, lp)                                                      \
    __builtin_amdgcn_global_load_lds(                                      \
        (const __attribute__((address_space(1))) void*)(gp),               \
        (__attribute__((address_space(3))) void*)(lp), 16, 0, 0)

// ---------------- CSR build (dst-sorted incoming edge lists) ----------------
__global__ void count_kernel(const int* __restrict__ ei, int* __restrict__ cnt) {
    int i = blockIdx.x * blockDim.x + threadIdx.x;
    if (i >= E2) return;
    int dst = (i < NEDGES) ? ei[NEDGES + i] : (i - NEDGES);
    atomicAdd(&cnt[dst], 1);
}

__global__ void scan_kernel(const int* __restrict__ cnt, int* __restrict__ indptr,
                            int* __restrict__ cursor) {
    __shared__ int part[1024];
    int tid = threadIdx.x;
    const int CH = (NNODES + 1023) / 1024;
    int base = tid * CH;
    int s = 0;
    for (int i = 0; i < CH; i++) {
        int idx = base + i;
        if (idx < NNODES) s += cnt[idx];
    }
    part[tid] = s;
    __syncthreads();
    for (int off = 1; off < 1024; off <<= 1) {
        int v = (tid >= off) ? part[tid - off] : 0;
        __syncthreads();
        part[tid] += v;
        __syncthreads();
    }
    int run = (tid == 0) ? 0 : part[tid - 1];
    for (int i = 0; i < CH; i++) {
        int idx = base + i;
        if (idx < NNODES) {
            indptr[idx] = run;
            cursor[idx] = run;
            run += cnt[idx];
        }
    }
    if (tid == 0) indptr[NNODES] = part[1023];
}

__global__ void scatter_kernel(const int* __restrict__ ei, int* __restrict__ cursor,
                               int* __restrict__ esrc) {
    int i = blockIdx.x * blockDim.x + threadIdx.x;
    if (i >= E2) return;
    int src, dst;
    if (i < NEDGES) {
        src = ei[i];
        dst = ei[NEDGES + i];
    } else {
        src = dst = i - NEDGES;
    }
    int pos = atomicAdd(&cursor[dst], 1);
    esrc[pos] = src;
}

// ---------------- fp32 -> bf16 hi/lo splits ----------------
__global__ void splitW1_kernel(const float* __restrict__ W1,
                               unsigned short* __restrict__ w1Hi,
                               unsigned short* __restrict__ w1Lo) {
    int k = threadIdx.x;  // 0..63
    int r = blockIdx.x;   // 0..1399
    float v = (k < F_IN) ? W1[(size_t)r * F_IN + k] : 0.f;
    unsigned short h = f2bf(v);
    w1Hi[(size_t)r * KP1 + k] = h;
    w1Lo[(size_t)r * KP1 + k] = f2bf(v - bf2f(h));
}

__global__ void splitB_kernel(const float* __restrict__ W2, const float* __restrict__ Wsk,
                              const float* __restrict__ W3,
                              unsigned short* __restrict__ w2Hi, unsigned short* __restrict__ w2Lo,
                              unsigned short* __restrict__ w3Hi, unsigned short* __restrict__ w3Lo) {
    int k = blockIdx.x * blockDim.x + threadIdx.x;
    if (k >= KP2) return;
    int r = blockIdx.y;
    const int K = 1400;
    const float* src;
    unsigned short *hi, *lo;
    int row;
    if (r < 1400) { src = W2; row = r; hi = w2Hi; lo = w2Lo; }
    else if (r < 2800) { src = Wsk; row = r - 1400; hi = w2Hi + (size_t)1400 * KP2; lo = w2Lo + (size_t)1400 * KP2; }
    else { src = W3; row = r - 2800; hi = w3Hi; lo = w3Lo; }
    float v = (k < K) ? src[(size_t)row * K + k] : 0.f;
    unsigned short h = f2bf(v);
    hi[(size_t)row * KP2 + k] = h;
    lo[(size_t)row * KP2 + k] = f2bf(v - bf2f(h));
}

// ---------------- a-tilde precompute: at[h][k] = sum_c W[h*C+c, k] * a[h,c] ----
__global__ void atil_kernel(const float* __restrict__ W, const float* __restrict__ av_s,
                            const float* __restrict__ av_d, float* __restrict__ outS,
                            float* __restrict__ outD, int C, int K, int cchunk) {
    int k = blockIdx.x * 64 + (threadIdx.x & 63);
    if (k >= K) return;
    int h = blockIdx.y;
    int c0 = blockIdx.z * cchunk;
    int c1 = c0 + cchunk;
    if (c1 > C) c1 = C;
    float ss = 0.f, dd = 0.f;
    for (int c = c0; c < c1; c++) {
        float wv = W[((size_t)h * C + c) * K + k];
        ss = fmaf(wv, av_s[h * C + c], ss);
        dd = fmaf(wv, av_d[h * C + c], dd);
    }
    atomicAdd(&outS[(size_t)h * K + k], ss);
    atomicAdd(&outD[(size_t)h * K + k], dd);
}

// ---------------- layer-1 alpha directly from x ----------------
__global__ __launch_bounds__(256) void alpha1x_kernel(const float* __restrict__ x,
                                                      const float* __restrict__ at1s,
                                                      const float* __restrict__ at1d,
                                                      float* __restrict__ as1,
                                                      float* __restrict__ ad1) {
    int wave = threadIdx.x >> 6, lane = threadIdx.x & 63;
    int n = blockIdx.x * 4 + wave;
    if (n >= NNODES) return;
    int kk = lane < F_IN ? lane : F_IN - 1;
    float v = (lane < F_IN) ? x[(size_t)n * F_IN + lane] : 0.f;
    float p[8];
#pragma unroll
    for (int h = 0; h < 4; h++) {
        p[h] = v * at1s[h * F_IN + kk];
        p[4 + h] = v * at1d[h * F_IN + kk];
    }
#pragma unroll
    for (int s = 0; s < 8; s++)
#pragma unroll
        for (int o = 32; o > 0; o >>= 1) p[s] += __shfl_xor(p[s], o, 64);
    if (lane == 0) {
#pragma unroll
        for (int h = 0; h < 4; h++) {
            as1[n * 4 + h] = p[h];
            ad1[n * 4 + h] = p[4 + h];
        }
    }
}

// ---------------- zero the K-pad columns of act (cols 1400..1407) -----------
__global__ void zeropad_kernel(unsigned short* __restrict__ hi,
                               unsigned short* __restrict__ lo) {
    int i = blockIdx.x * 256 + threadIdx.x;
    if (i >= NNODES * 8) return;
    int n = i >> 3, c = 1400 + (i & 7);
    hi[(size_t)n * KP2 + c] = 0;
    lo[(size_t)n * KP2 + c] = 0;
}

// ---------------- layer-1 aggregate-first: xagg[n, h*64+k] = sum_j a_jh x_j[k]
__global__ __launch_bounds__(256) void agg_x(
    const float* __restrict__ x, const float* __restrict__ as_n,
    const float* __restrict__ ad_n, const int* __restrict__ indptr,
    const int* __restrict__ esrc, unsigned short* __restrict__ xaggHi,
    unsigned short* __restrict__ xaggLo) {
    int n = blockIdx.x, tid = threadIdx.x;
    int s = indptr[n], e = indptr[n + 1];
    int deg = e - s;
    if (deg > MAXE) deg = MAXE;
    __shared__ int srcs[MAXE];
    __shared__ float wgt[MAXE * 4];

    if (tid < 64) {
        int lane = tid;
        float adv[4], mx[4], sm[4];
#pragma unroll
        for (int h = 0; h < 4; h++) {
            adv[h] = ad_n[n * 4 + h];
            mx[h] = -1e30f;
            sm[h] = 0.f;
        }
        for (int j = lane; j < deg; j += 64) {
            int sr = esrc[s + j];
            srcs[j] = sr;
#pragma unroll
            for (int h = 0; h < 4; h++) {
                float ev = as_n[sr * 4 + h] + adv[h];
                ev = ev > 0.f ? ev : 0.2f * ev;
                wgt[j * 4 + h] = ev;
                mx[h] = fmaxf(mx[h], ev);
            }
        }
#pragma unroll
        for (int h = 0; h < 4; h++)
#pragma unroll
            for (int o = 32; o > 0; o >>= 1) mx[h] = fmaxf(mx[h], __shfl_xor(mx[h], o, 64));
        for (int j = lane; j < deg; j += 64) {
#pragma unroll
            for (int h = 0; h < 4; h++) {
                float p = __expf(wgt[j * 4 + h] - mx[h]);
                wgt[j * 4 + h] = p;
                sm[h] += p;
            }
        }
#pragma unroll
        for (int h = 0; h < 4; h++) {
#pragma unroll
            for (int o = 32; o > 0; o >>= 1) sm[h] += __shfl_xor(sm[h], o, 64);
            sm[h] = 1.f / sm[h];
        }
        for (int j = lane; j < deg; j += 64) {
#pragma unroll
            for (int h = 0; h < 4; h++) wgt[j * 4 + h] *= sm[h];
        }
    }
    __syncthreads();

    int h = tid >> 6, k = tid & 63;
    float a = 0.f;
    if (k < F_IN) {
        int j = 0;
        float a2 = 0.f;
        for (; j + 1 < deg; j += 2) {
            a = fmaf(wgt[j * 4 + h], x[(size_t)srcs[j] * F_IN + k], a);
            a2 = fmaf(wgt[(j + 1) * 4 + h], x[(size_t)srcs[j + 1] * F_IN + k], a2);
        }
        if (j < deg) a = fmaf(wgt[j * 4 + h], x[(size_t)srcs[j] * F_IN + k], a);
        a += a2;
    }
    unsigned short hi = f2bf(a);
    xaggHi[(size_t)n * 256 + tid] = hi;
    xaggLo[(size_t)n * 256 + tid] = f2bf(a - bf2f(hi));  // k>=F_IN lanes write 0 (K-pad)
}

// ---------------- layer-1 per-head GEMM: act1 = ELU(W1_h . xagg_h + b1) -------
__global__ __launch_bounds__(256, 2) void gemm_h1(
    const unsigned short* __restrict__ xaggHi, const unsigned short* __restrict__ xaggLo,
    const unsigned short* __restrict__ w1Hi, const unsigned short* __restrict__ w1Lo,
    const float* __restrict__ bias, unsigned short* __restrict__ actHi,
    unsigned short* __restrict__ actLo) {
    __shared__ __align__(16) unsigned short sA[2][128 * 32];
    __shared__ __align__(16) unsigned short sB[2][256 * 32];
    int tid = threadIdx.x;
    int wave = tid >> 6, lane = tid & 63;
    int wm = (wave >> 1) * 64, wn = (wave & 1) * 128;
    int fr = lane & 15, kq = lane >> 4;
    int row0 = blockIdx.y * 128, col0 = blockIdx.x * 256;
    int hd = blockIdx.z;

    floatx4 acc[4][8];
#pragma unroll
    for (int i = 0; i < 4; i++)
#pragma unroll
        for (int j = 0; j < 8; j++)
#pragma unroll
            for (int q = 0; q < 4; q++) acc[i][j][q] = 0.f;

    int gpos = lane & 3;
    int rl = lane >> 2;
    int gsw = kq ^ ((fr >> 1) & 3);

    for (int k0 = 0; k0 < 64; k0 += 32) {
#pragma unroll
        for (int c = 0; c < 2; ++c) {
            int r = wave * 32 + c * 16 + rl;
            int g = gpos ^ ((r >> 1) & 3);
            size_t gofs = (size_t)(row0 + r) * 256 + hd * 64 + k0 + g * 8;
            size_t lofs = (size_t)r * 32 + (size_t)gpos * 8;
            GLL16(xaggHi + gofs, &sA[0][lofs]);
            GLL16(xaggLo + gofs, &sA[1][lofs]);
        }
#pragma unroll
        for (int c = 0; c < 4; ++c) {
            int r = wave * 64 + c * 16 + rl;
            int g = gpos ^ ((r >> 1) & 3);
            size_t gofs = (size_t)(hd * 350 + col0 + r) * KP1 + k0 + g * 8;
            size_t lofs = (size_t)r * 32 + (size_t)gpos * 8;
            GLL16(w1Hi + gofs, &sB[0][lofs]);
            GLL16(w1Lo + gofs, &sB[1][lofs]);
        }
        __syncthreads();

        short8 ah[4], al[4], bh[8], bl[8];
#pragma unroll
        for (int j = 0; j < 8; j++) {
            int rb = wn + j * 16 + fr;
            bh[j] = *(const short8*)&sB[0][rb * 32 + gsw * 8];
            bl[j] = *(const short8*)&sB[1][rb * 32 + gsw * 8];
        }
#pragma unroll
        for (int i = 0; i < 4; i++) {
            int ra = wm + i * 16 + fr;
            ah[i] = *(const short8*)&sA[0][ra * 32 + gsw * 8];
            al[i] = *(const short8*)&sA[1][ra * 32 + gsw * 8];
        }
#pragma unroll
        for (int i = 0; i < 4; i++)
#pragma unroll
            for (int j = 0; j < 8; j++) {
                acc[i][j] = __builtin_amdgcn_mfma_f32_16x16x32_bf16(ah[i], bh[j],
                                                                   acc[i][j], 0, 0, 0);
                acc[i][j] = __builtin_amdgcn_mfma_f32_16x16x32_bf16(al[i], bh[j],
                                                                   acc[i][j], 0, 0, 0);
                acc[i][j] = __builtin_amdgcn_mfma_f32_16x16x32_bf16(ah[i], bl[j],
                                                                   acc[i][j], 0, 0, 0);
            }
        __syncthreads();
    }

#pragma unroll
    for (int i = 0; i < 4; i++) {
#pragma unroll
        for (int rg = 0; rg < 4; rg++) {
            int rr = row0 + wm + i * 16 + kq * 4 + rg;
            if (rr >= NNODES) continue;
#pragma unroll
            for (int j = 0; j < 8; j++) {
                int cc = col0 + wn + j * 16 + fr;
                if (cc < 350) {
                    int gc = hd * 350 + cc;
                    float v = acc[i][j][rg] + bias[gc];
                    v = v > 0.f ? v : expm1f(v);
                    unsigned short hi = f2bf(v);
                    actHi[(size_t)rr * KP2 + gc] = hi;
                    actLo[(size_t)rr * KP2 + gc] = f2bf(v - bf2f(hi));
                }
            }
        }
    }
}

// ---------------- alpha from act (hi/lo planes): a[n,h] = act . at[h,:] ------
__global__ __launch_bounds__(256) void alpha_act(
    const unsigned short* __restrict__ actHi, const unsigned short* __restrict__ actLo,
    const float* __restrict__ ats, const float* __restrict__ atd,
    float* __restrict__ asx, float* __restrict__ adx) {
    int wave = threadIdx.x >> 6, lane = threadIdx.x & 63;
    int n = blockIdx.x * 4 + wave;
    if (n >= NNODES) return;
    float p[8] = {0.f, 0.f, 0.f, 0.f, 0.f, 0.f, 0.f, 0.f};
    for (int k = lane; k < 1400; k += 64) {
        float v = bf2f(actHi[(size_t)n * KP2 + k]) + bf2f(actLo[(size_t)n * KP2 + k]);
#pragma unroll
        for (int h = 0; h < 4; h++) {
            p[h] = fmaf(v, ats[h * 1400 + k], p[h]);
            p[4 + h] = fmaf(v, atd[h * 1400 + k], p[4 + h]);
        }
    }
#pragma unroll
    for (int q = 0; q < 8; q++)
#pragma unroll
        for (int o = 32; o > 0; o >>= 1) p[q] += __shfl_xor(p[q], o, 64);
    if (lane == 0) {
#pragma unroll
        for (int h = 0; h < 4; h++) {
            asx[n * 4 + h] = p[h];
            adx[n * 4 + h] = p[4 + h];
        }
    }
}

// ---------------- split-bf16 MFMA GEMM, 128x256 tile ----------------
__global__ __launch_bounds__(256, 2) void gemm_hilo(
    const unsigned short* __restrict__ Ahi, const unsigned short* __restrict__ Alo,
    const unsigned short* __restrict__ Bhi, const unsigned short* __restrict__ Blo,
    float* __restrict__ C, int NN, int M, int Kp, int ldc) {
    __shared__ __align__(16) unsigned short sA[2][128 * 32];
    __shared__ __align__(16) unsigned short sB[2][256 * 32];
    int tid = threadIdx.x;
    int wave = tid >> 6, lane = tid & 63;
    int wm = (wave >> 1) * 64, wn = (wave & 1) * 128;
    int fr = lane & 15, kq = lane >> 4;
    int row0 = blockIdx.y * 128, col0 = blockIdx.x * 256;

    floatx4 acc[4][8];
#pragma unroll
    for (int i = 0; i < 4; i++)
#pragma unroll
        for (int j = 0; j < 8; j++)
#pragma unroll
            for (int q = 0; q < 4; q++) acc[i][j][q] = 0.f;

    int gpos = lane & 3;
    int rl = lane >> 2;
    int gsw = kq ^ ((fr >> 1) & 3);

    for (int k0 = 0; k0 < Kp; k0 += 32) {
#pragma unroll
        for (int c = 0; c < 2; ++c) {
            int r = wave * 32 + c * 16 + rl;
            int g = gpos ^ ((r >> 1) & 3);
            size_t gofs = (size_t)(row0 + r) * Kp + k0 + g * 8;
            size_t lofs = (size_t)r * 32 + (size_t)gpos * 8;
            GLL16(Ahi + gofs, &sA[0][lofs]);
            GLL16(Alo + gofs, &sA[1][lofs]);
        }
#pragma unroll
        for (int c = 0; c < 4; ++c) {
            int r = wave * 64 + c * 16 + rl;
            int g = gpos ^ ((r >> 1) & 3);
            size_t gofs = (size_t)(col0 + r) * Kp + k0 + g * 8;
            size_t lofs = (size_t)r * 32 + (size_t)gpos * 8;
            GLL16(Bhi + gofs, &sB[0][lofs]);
            GLL16(Blo + gofs, &sB[1][lofs]);
        }
        __syncthreads();

        short8 ah[4], al[4], bh[8], bl[8];
#pragma unroll
        for (int j = 0; j < 8; j++) {
            int rb = wn + j * 16 + fr;
            bh[j] = *(const short8*)&sB[0][rb * 32 + gsw * 8];
            bl[j] = *(const short8*)&sB[1][rb * 32 + gsw * 8];
        }
#pragma unroll
        for (int i = 0; i < 4; i++) {
            int ra = wm + i * 16 + fr;
            ah[i] = *(const short8*)&sA[0][ra * 32 + gsw * 8];
            al[i] = *(const short8*)&sA[1][ra * 32 + gsw * 8];
        }
#pragma unroll
        for (int i = 0; i < 4; i++)
#pragma unroll
            for (int j = 0; j < 8; j++) {
                acc[i][j] = __builtin_amdgcn_mfma_f32_16x16x32_bf16(ah[i], bh[j],
                                                                   acc[i][j], 0, 0, 0);
                acc[i][j] = __builtin_amdgcn_mfma_f32_16x16x32_bf16(al[i], bh[j],
                                                                   acc[i][j], 0, 0, 0);
                acc[i][j] = __builtin_amdgcn_mfma_f32_16x16x32_bf16(ah[i], bl[j],
                                                                   acc[i][j], 0, 0, 0);
            }
        __syncthreads();
    }

#pragma unroll
    for (int i = 0; i < 4; i++) {
#pragma unroll
        for (int rg = 0; rg < 4; rg++) {
            int rr = row0 + wm + i * 16 + kq * 4 + rg;
            if (rr >= NN) continue;
#pragma unroll
            for (int j = 0; j < 8; j++) {
                int cc = col0 + wn + j * 16 + fr;
                if (cc < M) C[(size_t)rr * ldc + cc] = acc[i][j][rg];
            }
        }
    }
}

// ---------------- softmax-weighted aggregation, one block per dst node -------
#define AGG_T 384
template <int H, int C, int MODE, int DOELU, int SKIP, int HN>
__global__ __launch_bounds__(AGG_T) void agg2(
    const float* __restrict__ hpre, int ldh, const float* __restrict__ skip,
    const float* __restrict__ as_n, const float* __restrict__ ad_n,
    const int* __restrict__ indptr, const int* __restrict__ esrc,
    const float* __restrict__ bias, unsigned short* __restrict__ outHi,
    unsigned short* __restrict__ outLo, int Kp, float* __restrict__ outF,
    const float* __restrict__ atns, const float* __restrict__ atnd,
    float* __restrict__ asx, float* __restrict__ adx) {
    constexpr int HC = H * C;
    int n = blockIdx.x;
    int tid = threadIdx.x;
    int s = indptr[n], e = indptr[n + 1];
    int deg = e - s;
    if (deg > MAXE) deg = MAXE;

    __shared__ int srcs[MAXE];
    __shared__ float wgt[MAXE * H];
    __shared__ float aggsh[MODE ? HC : 1];
    __shared__ float sAl[16];
    if (tid < 16) sAl[tid] = 0.f;

    if (tid < 64) {
        int lane = tid;
        float adv[H], mx[H], sm[H];
#pragma unroll
        for (int h = 0; h < H; h++) {
            adv[h] = ad_n[n * H + h];
            mx[h] = -1e30f;
            sm[h] = 0.f;
        }
        for (int j = lane; j < deg; j += 64) {
            int sr = esrc[s + j];
            srcs[j] = sr;
#pragma unroll
            for (int h = 0; h < H; h++) {
                float ev = as_n[sr * H + h] + adv[h];
                ev = ev > 0.f ? ev : 0.2f * ev;
                wgt[j * H + h] = ev;
                mx[h] = fmaxf(mx[h], ev);
            }
        }
#pragma unroll
        for (int h = 0; h < H; h++)
#pragma unroll
            for (int o = 32; o > 0; o >>= 1) mx[h] = fmaxf(mx[h], __shfl_xor(mx[h], o, 64));
        for (int j = lane; j < deg; j += 64) {
#pragma unroll
            for (int h = 0; h < H; h++) {
                float p = __expf(wgt[j * H + h] - mx[h]);
                wgt[j * H + h] = p;
                sm[h] += p;
            }
        }
#pragma unroll
        for (int h = 0; h < H; h++) {
#pragma unroll
            for (int o = 32; o > 0; o >>= 1) sm[h] += __shfl_xor(sm[h], o, 64);
            sm[h] = 1.f / sm[h];
        }
        for (int j = lane; j < deg; j += 64) {
#pragma unroll
            for (int h = 0; h < H; h++) wgt[j * H + h] *= sm[h];
        }
    }
    __syncthreads();

    if (MODE == 0) {
        constexpr int NV4 = HC / 4;
        constexpr int NP = (HN > 0) ? 2 * HN : 1;
        float p[NP];
#pragma unroll
        for (int q = 0; q < NP; q++) p[q] = 0.f;

        for (int c4 = tid; c4 < NV4; c4 += AGG_T) {
            int cb = c4 * 4;
            int h0 = (cb + 0) / C, h1 = (cb + 1) / C;
            int h2c = (cb + 2) / C, h3 = (cb + 3) / C;
            float ax = 0.f, ay = 0.f, az = 0.f, aw = 0.f;
            int j = 0;
            for (; j + 3 < deg; j += 4) {
                const float4 v0 = *(const float4*)(hpre + (size_t)srcs[j] * ldh + cb);
                const float4 v1 = *(const float4*)(hpre + (size_t)srcs[j + 1] * ldh + cb);
                const float4 v2 = *(const float4*)(hpre + (size_t)srcs[j + 2] * ldh + cb);
                const float4 v3 = *(const float4*)(hpre + (size_t)srcs[j + 3] * ldh + cb);
                const float* w0 = &wgt[j * H];
                const float* w1 = &wgt[(j + 1) * H];
                const float* w2 = &wgt[(j + 2) * H];
                const float* w3 = &wgt[(j + 3) * H];
                ax = fmaf(w0[h0], v0.x, ax); ay = fmaf(w0[h1], v0.y, ay);
                az = fmaf(w0[h2c], v0.z, az); aw = fmaf(w0[h3], v0.w, aw);
                ax = fmaf(w1[h0], v1.x, ax); ay = fmaf(w1[h1], v1.y, ay);
                az = fmaf(w1[h2c], v1.z, az); aw = fmaf(w1[h3], v1.w, aw);
                ax = fmaf(w2[h0], v2.x, ax); ay = fmaf(w2[h1], v2.y, ay);
                az = fmaf(w2[h2c], v2.z, az); aw = fmaf(w2[h3], v2.w, aw);
                ax = fmaf(w3[h0], v3.x, ax); ay = fmaf(w3[h1], v3.y, ay);
                az = fmaf(w3[h2c], v3.z, az); aw = fmaf(w3[h3], v3.w, aw);
            }
            for (; j < deg; j++) {
                const float4 v0 = *(const float4*)(hpre + (size_t)srcs[j] * ldh + cb);
                const float* w0 = &wgt[j * H];
                ax = fmaf(w0[h0], v0.x, ax); ay = fmaf(w0[h1], v0.y, ay);
                az = fmaf(w0[h2c], v0.z, az); aw = fmaf(w0[h3], v0.w, aw);
            }
            ax += bias[cb + 0];
            ay += bias[cb + 1];
            az += bias[cb + 2];
            aw += bias[cb + 3];
            if (DOELU) {
                ax = ax > 0.f ? ax : expm1f(ax);
                ay = ay > 0.f ? ay : expm1f(ay);
                az = az > 0.f ? az : expm1f(az);
                aw = aw > 0.f ? aw : expm1f(aw);
            }
            if (SKIP) {
                const float4 sk = *(const float4*)(skip + (size_t)n * ldh + cb);
                ax += sk.x;
                ay += sk.y;
                az += sk.z;
                aw += sk.w;
            }
            if (HN > 0) {
                float vq[4] = {ax, ay, az, aw};
#pragma unroll
                for (int h = 0; h < HN; h++) {
                    float ss = 0.f, dd = 0.f;
#pragma unroll
                    for (int q = 0; q < 4; q++) {
                        ss = fmaf(vq[q], atns[(size_t)h * HC + cb + q], ss);
                        dd = fmaf(vq[q], atnd[(size_t)h * HC + cb + q], dd);
                    }
                    p[h] += ss;
                    p[HN + h] += dd;
                }
            }
            ushort4 hi4, lo4;
            hi4.x = f2bf(ax); lo4.x = f2bf(ax - bf2f(hi4.x));
            hi4.y = f2bf(ay); lo4.y = f2bf(ay - bf2f(hi4.y));
            hi4.z = f2bf(az); lo4.z = f2bf(az - bf2f(hi4.z));
            hi4.w = f2bf(aw); lo4.w = f2bf(aw - bf2f(hi4.w));
            *(ushort4*)(outHi + (size_t)n * Kp + cb) = hi4;
            *(ushort4*)(outLo + (size_t)n * Kp + cb) = lo4;
        }
        for (int c = HC + tid; c < Kp; c += AGG_T) {
            outHi[(size_t)n * Kp + c] = 0;
            outLo[(size_t)n * Kp + c] = 0;
        }
        if (HN > 0) {
#pragma unroll
            for (int q = 0; q < NP; q++)
#pragma unroll
                for (int o = 32; o > 0; o >>= 1) p[q] += __shfl_xor(p[q], o, 64);
            if ((tid & 63) == 0) {
#pragma unroll
                for (int q = 0; q < NP; q++) atomicAdd(&sAl[q], p[q]);
            }
            __syncthreads();
            if (tid < HN) asx[n * HN + tid] = sAl[tid];
            else if (tid < 2 * HN) adx[n * HN + (tid - HN)] = sAl[tid];
        }
    } else {
        for (int cc = tid; cc < HC; cc += AGG_T) {
            int h = cc / C;
            float a = 0.f;
            for (int j = 0; j < deg; ++j)
                a = fmaf(wgt[j * H + h], hpre[(size_t)srcs[j] * ldh + cc], a);
            aggsh[cc] = a;
        }
        __syncthreads();
        for (int c = tid; c < C; c += AGG_T) {
            float sres = 0.f;
#pragma unroll
            for (int h = 0; h < H; h++) sres += aggsh[h * C + c];
            outF[(size_t)n * C + c] = sres * (1.f / (float)H) + bias[c];
        }
    }
}

// ---------------- launcher ----------------
extern "C" void kernel_launch(void* const* d_in, const int* in_sizes, int n_in,
                              void* d_out, int out_size, void* d_ws, size_t ws_size,
                              hipStream_t stream) {
    const float* x = (const float*)d_in[0];
    const int* ei = (const int*)d_in[1];
    const float* W1 = (const float*)d_in[2];
    const float* a1s = (const float*)d_in[3];
    const float* a1d = (const float*)d_in[4];
    const float* b1 = (const float*)d_in[5];
    const float* W2 = (const float*)d_in[6];
    const float* a2s = (const float*)d_in[7];
    const float* a2d = (const float*)d_in[8];
    const float* b2 = (const float*)d_in[9];
    const float* Wsk = (const float*)d_in[10];
    const float* W3 = (const float*)d_in[11];
    const float* a3s = (const float*)d_in[12];
    const float* a3d = (const float*)d_in[13];
    const float* b3 = (const float*)d_in[14];
    float* out = (float*)d_out;

    char* w = (char*)d_ws;
    size_t off = 0;
    auto alloc = [&](size_t bytes) -> char* {
        char* p = w + off;
        off += (bytes + 255) & ~(size_t)255;
        return p;
    };
    float* hpre = (float*)alloc((size_t)NNODES * 2800 * 4);
    unsigned short* actHi = (unsigned short*)alloc((size_t)(NNODES + ROWSLACK) * KP2 * 2);
    unsigned short* actLo = (unsigned short*)alloc((size_t)(NNODES + ROWSLACK) * KP2 * 2);
    unsigned short* xaggHi = (unsigned short*)alloc((size_t)(NNODES + ROWSLACK) * 256 * 2);
    unsigned short* xaggLo = (unsigned short*)alloc((size_t)(NNODES + ROWSLACK) * 256 * 2);
    unsigned short* w1Hi = (unsigned short*)alloc((size_t)(1400 + 512) * KP1 * 2);
    unsigned short* w1Lo = (unsigned short*)alloc((size_t)(1400 + 512) * KP1 * 2);
    unsigned short* w2Hi = (unsigned short*)alloc((size_t)(2800 + ROWSLACK) * KP2 * 2);
    unsigned short* w2Lo = (unsigned short*)alloc((size_t)(2800 + ROWSLACK) * KP2 * 2);
    unsigned short* w3Hi = (unsigned short*)alloc((size_t)(726 + ROWSLACK) * KP2 * 2);
    unsigned short* w3Lo = (unsigned short*)alloc((size_t)(726 + ROWSLACK) * KP2 * 2);
    // zero block: atall (28400 floats) + cnt (NNODES+16 ints), contiguous
    float* atall = (float*)alloc((size_t)28400 * 4);
    int* cnt = (int*)alloc((size_t)(NNODES + 16) * 4);
    float* at1s = atall;
    float* at1d = atall + 200;
    float* at2s = atall + 400;
    float* at2d = atall + 6000;
    float* at3s = atall + 11600;
    float* at3d = atall + 20000;
    float* asP = (float*)alloc((size_t)NNODES * 6 * 4);
    float* adP = (float*)alloc((size_t)NNODES * 6 * 4);
    float* asQ = (float*)alloc((size_t)NNODES * 6 * 4);
    float* adQ = (float*)alloc((size_t)NNODES * 6 * 4);
    int* indptr = (int*)alloc((size_t)(NNODES + 16) * 4);
    int* cursor = (int*)alloc((size_t)(NNODES + 16) * 4);
    int* esrc = (int*)alloc((size_t)E2 * 4);

    // ---- one memset for atomic-accumulated + counter buffers ----
    size_t zbytes = (size_t)((char*)cnt - (char*)atall) + (NNODES + 16) * 4;
    hipMemsetAsync(atall, 0, zbytes, stream);

    // ---- weight hi/lo splits + a-tilde precompute ----
    splitW1_kernel<<<1400, 64, 0, stream>>>(W1, w1Hi, w1Lo);
    splitB_kernel<<<dim3(6, 2800 + 726), 256, 0, stream>>>(W2, Wsk, W3, w2Hi, w2Lo,
                                                           w3Hi, w3Lo);
    atil_kernel<<<dim3(1, 4, 5), 64, 0, stream>>>(W1, a1s, a1d, at1s, at1d, HIDC, F_IN, 70);
    atil_kernel<<<dim3(22, 4, 5), 64, 0, stream>>>(W2, a2s, a2d, at2s, at2d, HIDC, 1400, 70);
    atil_kernel<<<dim3(22, 6, 4), 64, 0, stream>>>(W3, a3s, a3d, at3s, at3d, OUTC, 1400, 31);
    alpha1x_kernel<<<(NNODES + 3) / 4, 256, 0, stream>>>(x, at1s, at1d, asP, adP);

    // ---- CSR build ----
    count_kernel<<<(E2 + 255) / 256, 256, 0, stream>>>(ei, cnt);
    scan_kernel<<<1, 1024, 0, stream>>>(cnt, indptr, cursor);
    scatter_kernel<<<(E2 + 255) / 256, 256, 0, stream>>>(ei, cursor, esrc);

    // ---- zero act K-pad columns (act1 path writes only cols 0..1399) ----
    zeropad_kernel<<<(NNODES * 8 + 255) / 256, 256, 0, stream>>>(actHi, actLo);

    dim3 blk(256);
    int gy = (NNODES + 127) / 128;  // 79

    // ---- Layer 1: aggregate-first ----
    agg_x<<<NNODES, 256, 0, stream>>>(x, asP, adP, indptr, esrc, xaggHi, xaggLo);
    gemm_h1<<<dim3(2, gy, 4), blk, 0, stream>>>(xaggHi, xaggLo, w1Hi, w1Lo, b1,
                                                actHi, actLo);
    alpha_act<<<(NNODES + 3) / 4, 256, 0, stream>>>(actHi, actLo, at2s, at2d, asQ, adQ);

    // ---- Layer 2 (fused with skip: B = [W2; Wskip], M = 2800) ----
    {
        int HC = NH2 * HIDC;  // 1400
        int M = 2 * HC;       // 2800
        dim3 grid((M + 255) / 256, gy);
        gemm_hilo<<<grid, blk, 0, stream>>>(actHi, actLo, w2Hi, w2Lo, hpre, NNODES, M, KP2, M);
        // agg reads alpha2 (Q), writes act2 + alpha3 (P)
        agg2<NH2, HIDC, 0, 1, 1, 6><<<NNODES, AGG_T, 0, stream>>>(
            hpre, M, hpre + HC, asQ, adQ, indptr, esrc, b2, actHi, actLo, KP2, nullptr,
            at3s, at3d, asP, adP);
    }
    // ---- Layer 3 ----
    {
        int M = NH3 * OUTC;  // 726
        dim3 grid((M + 255) / 256, gy);
        gemm_hilo<<<grid, blk, 0, stream>>>(actHi, actLo, w3Hi, w3Lo, hpre, NNODES, M, KP2, M);
        agg2<NH3, OUTC, 1, 0, 0, 0><<<NNODES, AGG_T, 0, stream>>>(
            hpre, M, nullptr, asP, adP, indptr, esrc, b3, nullptr, nullptr, 0, out,
            nullptr, nullptr, nullptr, nullptr);
    }
}

// Round 7
// 800.978 us; speedup vs baseline: 1.1285x; 1.1043x over previous
//
#include <hip/hip_runtime.h>
#include <math.h>

#define NNODES 10000
#define NEDGES 160000
#define E2 (NEDGES + NNODES)
#define F_IN 50
#define HIDC 350
#define NH1 4
#define NH2 4
#define NH3 6
#define OUTC 121
#define MAXE 512
#define KP1 64      // F_IN=50 padded to 64
#define KP2 1408    // 1400 padded to 1408
#define ROWSLACK 128

typedef __attribute__((ext_vector_type(8))) short short8;
typedef __attribute__((ext_vector_type(4))) float floatx4;

static __device__ __forceinline__ unsigned short f2bf(float f) {
    unsigned u = __float_as_uint(f);
    unsigned r = (u + 0x7fffu + ((u >> 16) & 1u)) >> 16;
    return (unsigned short)r;
}
static __device__ __forceinline__ float bf2f(unsigned short s) {
    return __uint_as_float(((unsigned)s) << 16);
}

// async global->LDS, 16 bytes per lane; LDS dest is wave-uniform base + lane*16
#define GLL16(gp, lp)                                                      \
    __builtin_amdgcn_global_load_lds(                                      \
        (const __attribute__((address_space(1))) void*)(gp),               \
        (__attribute__((address_space(3))) void*)(lp), 16, 0, 0)

// ---------------- CSR build (dst-sorted incoming edge lists) ----------------
__global__ void count_kernel(const int* __restrict__ ei, int* __restrict__ cnt) {
    int i = blockIdx.x * blockDim.x + threadIdx.x;
    if (i >= E2) return;
    int dst = (i < NEDGES) ? ei[NEDGES + i] : (i - NEDGES);
    atomicAdd(&cnt[dst], 1);
}

__global__ void scan_kernel(const int* __restrict__ cnt, int* __restrict__ indptr,
                            int* __restrict__ cursor) {
    __shared__ int part[1024];
    int tid = threadIdx.x;
    const int CH = (NNODES + 1023) / 1024;
    int base = tid * CH;
    int s = 0;
    for (int i = 0; i < CH; i++) {
        int idx = base + i;
        if (idx < NNODES) s += cnt[idx];
    }
    part[tid] = s;
    __syncthreads();
    for (int off = 1; off < 1024; off <<= 1) {
        int v = (tid >= off) ? part[tid - off] : 0;
        __syncthreads();
        part[tid] += v;
        __syncthreads();
    }
    int run = (tid == 0) ? 0 : part[tid - 1];
    for (int i = 0; i < CH; i++) {
        int idx = base + i;
        if (idx < NNODES) {
            indptr[idx] = run;
            cursor[idx] = run;
            run += cnt[idx];
        }
    }
    if (tid == 0) indptr[NNODES] = part[1023];
}

__global__ void scatter_kernel(const int* __restrict__ ei, int* __restrict__ cursor,
                               int* __restrict__ esrc) {
    int i = blockIdx.x * blockDim.x + threadIdx.x;
    if (i >= E2) return;
    int src, dst;
    if (i < NEDGES) {
        src = ei[i];
        dst = ei[NEDGES + i];
    } else {
        src = dst = i - NEDGES;
    }
    int pos = atomicAdd(&cursor[dst], 1);
    esrc[pos] = src;
}

// ---------------- fp32 -> bf16 hi/lo splits ----------------
__global__ void splitW1_kernel(const float* __restrict__ W1,
                               unsigned short* __restrict__ w1Hi,
                               unsigned short* __restrict__ w1Lo) {
    int k = threadIdx.x;  // 0..63
    int r = blockIdx.x;   // 0..1399
    float v = (k < F_IN) ? W1[(size_t)r * F_IN + k] : 0.f;
    unsigned short h = f2bf(v);
    w1Hi[(size_t)r * KP1 + k] = h;
    w1Lo[(size_t)r * KP1 + k] = f2bf(v - bf2f(h));
}

// hi-only split for W2/Wskip/W3 (2-product GEMM drops B-lo)
__global__ void splitB_kernel(const float* __restrict__ W2, const float* __restrict__ Wsk,
                              const float* __restrict__ W3,
                              unsigned short* __restrict__ w2Hi,
                              unsigned short* __restrict__ w3Hi) {
    int k = blockIdx.x * blockDim.x + threadIdx.x;
    if (k >= KP2) return;
    int r = blockIdx.y;
    const int K = 1400;
    const float* src;
    unsigned short* hi;
    int row;
    if (r < 1400) { src = W2; row = r; hi = w2Hi; }
    else if (r < 2800) { src = Wsk; row = r - 1400; hi = w2Hi + (size_t)1400 * KP2; }
    else { src = W3; row = r - 2800; hi = w3Hi; }
    float v = (k < K) ? src[(size_t)row * K + k] : 0.f;
    hi[(size_t)row * KP2 + k] = f2bf(v);
}

// ---------------- a-tilde precompute: at[h][k] = sum_c W[h*C+c, k] * a[h,c] ----
__global__ void atil_kernel(const float* __restrict__ W, const float* __restrict__ av_s,
                            const float* __restrict__ av_d, float* __restrict__ outS,
                            float* __restrict__ outD, int C, int K, int cchunk) {
    int k = blockIdx.x * 64 + (threadIdx.x & 63);
    if (k >= K) return;
    int h = blockIdx.y;
    int c0 = blockIdx.z * cchunk;
    int c1 = c0 + cchunk;
    if (c1 > C) c1 = C;
    float ss = 0.f, dd = 0.f;
    for (int c = c0; c < c1; c++) {
        float wv = W[((size_t)h * C + c) * K + k];
        ss = fmaf(wv, av_s[h * C + c], ss);
        dd = fmaf(wv, av_d[h * C + c], dd);
    }
    atomicAdd(&outS[(size_t)h * K + k], ss);
    atomicAdd(&outD[(size_t)h * K + k], dd);
}

// ---------------- layer-1 alpha directly from x ----------------
__global__ __launch_bounds__(256) void alpha1x_kernel(const float* __restrict__ x,
                                                      const float* __restrict__ at1s,
                                                      const float* __restrict__ at1d,
                                                      float* __restrict__ as1,
                                                      float* __restrict__ ad1) {
    int wave = threadIdx.x >> 6, lane = threadIdx.x & 63;
    int n = blockIdx.x * 4 + wave;
    if (n >= NNODES) return;
    int kk = lane < F_IN ? lane : F_IN - 1;
    float v = (lane < F_IN) ? x[(size_t)n * F_IN + lane] : 0.f;
    float p[8];
#pragma unroll
    for (int h = 0; h < 4; h++) {
        p[h] = v * at1s[h * F_IN + kk];
        p[4 + h] = v * at1d[h * F_IN + kk];
    }
#pragma unroll
    for (int s = 0; s < 8; s++)
#pragma unroll
        for (int o = 32; o > 0; o >>= 1) p[s] += __shfl_xor(p[s], o, 64);
    if (lane == 0) {
#pragma unroll
        for (int h = 0; h < 4; h++) {
            as1[n * 4 + h] = p[h];
            ad1[n * 4 + h] = p[4 + h];
        }
    }
}

// ---------------- zero the K-pad columns of act (cols 1400..1407) -----------
__global__ void zeropad_kernel(unsigned short* __restrict__ hi,
                               unsigned short* __restrict__ lo) {
    int i = blockIdx.x * 256 + threadIdx.x;
    if (i >= NNODES * 8) return;
    int n = i >> 3, c = 1400 + (i & 7);
    hi[(size_t)n * KP2 + c] = 0;
    lo[(size_t)n * KP2 + c] = 0;
}

// ---------------- layer-1 aggregate-first: xagg[n, h*64+k] = sum_j a_jh x_j[k]
__global__ __launch_bounds__(256) void agg_x(
    const float* __restrict__ x, const float* __restrict__ as_n,
    const float* __restrict__ ad_n, const int* __restrict__ indptr,
    const int* __restrict__ esrc, unsigned short* __restrict__ xaggHi,
    unsigned short* __restrict__ xaggLo) {
    int n = blockIdx.x, tid = threadIdx.x;
    int s = indptr[n], e = indptr[n + 1];
    int deg = e - s;
    if (deg > MAXE) deg = MAXE;
    __shared__ int srcs[MAXE];
    __shared__ float wgt[MAXE * 4];

    if (tid < 64) {
        int lane = tid;
        float adv[4], mx[4], sm[4];
#pragma unroll
        for (int h = 0; h < 4; h++) {
            adv[h] = ad_n[n * 4 + h];
            mx[h] = -1e30f;
            sm[h] = 0.f;
        }
        for (int j = lane; j < deg; j += 64) {
            int sr = esrc[s + j];
            srcs[j] = sr;
#pragma unroll
            for (int h = 0; h < 4; h++) {
                float ev = as_n[sr * 4 + h] + adv[h];
                ev = ev > 0.f ? ev : 0.2f * ev;
                wgt[j * 4 + h] = ev;
                mx[h] = fmaxf(mx[h], ev);
            }
        }
#pragma unroll
        for (int h = 0; h < 4; h++)
#pragma unroll
            for (int o = 32; o > 0; o >>= 1) mx[h] = fmaxf(mx[h], __shfl_xor(mx[h], o, 64));
        for (int j = lane; j < deg; j += 64) {
#pragma unroll
            for (int h = 0; h < 4; h++) {
                float p = __expf(wgt[j * 4 + h] - mx[h]);
                wgt[j * 4 + h] = p;
                sm[h] += p;
            }
        }
#pragma unroll
        for (int h = 0; h < 4; h++) {
#pragma unroll
            for (int o = 32; o > 0; o >>= 1) sm[h] += __shfl_xor(sm[h], o, 64);
            sm[h] = 1.f / sm[h];
        }
        for (int j = lane; j < deg; j += 64) {
#pragma unroll
            for (int h = 0; h < 4; h++) wgt[j * 4 + h] *= sm[h];
        }
    }
    __syncthreads();

    int h = tid >> 6, k = tid & 63;
    float a = 0.f;
    if (k < F_IN) {
        int j = 0;
        float a2 = 0.f;
        for (; j + 1 < deg; j += 2) {
            a = fmaf(wgt[j * 4 + h], x[(size_t)srcs[j] * F_IN + k], a);
            a2 = fmaf(wgt[(j + 1) * 4 + h], x[(size_t)srcs[j + 1] * F_IN + k], a2);
        }
        if (j < deg) a = fmaf(wgt[j * 4 + h], x[(size_t)srcs[j] * F_IN + k], a);
        a += a2;
    }
    unsigned short hi = f2bf(a);
    xaggHi[(size_t)n * 256 + tid] = hi;
    xaggLo[(size_t)n * 256 + tid] = f2bf(a - bf2f(hi));  // k>=F_IN lanes write 0 (K-pad)
}

// ---------------- layer-1 per-head GEMM: act1 = ELU(W1_h . xagg_h + b1) -------
// full 3-product split (layer-1 accuracy feeds everything downstream)
__global__ __launch_bounds__(256, 2) void gemm_h1(
    const unsigned short* __restrict__ xaggHi, const unsigned short* __restrict__ xaggLo,
    const unsigned short* __restrict__ w1Hi, const unsigned short* __restrict__ w1Lo,
    const float* __restrict__ bias, unsigned short* __restrict__ actHi,
    unsigned short* __restrict__ actLo) {
    __shared__ __align__(16) unsigned short sA[2][128 * 32];
    __shared__ __align__(16) unsigned short sB[2][256 * 32];
    int tid = threadIdx.x;
    int wave = tid >> 6, lane = tid & 63;
    int wm = (wave >> 1) * 64, wn = (wave & 1) * 128;
    int fr = lane & 15, kq = lane >> 4;
    int row0 = blockIdx.y * 128, col0 = blockIdx.x * 256;
    int hd = blockIdx.z;

    floatx4 acc[4][8];
#pragma unroll
    for (int i = 0; i < 4; i++)
#pragma unroll
        for (int j = 0; j < 8; j++)
#pragma unroll
            for (int q = 0; q < 4; q++) acc[i][j][q] = 0.f;

    int gpos = lane & 3;
    int rl = lane >> 2;
    int gsw = kq ^ ((fr >> 1) & 3);

    for (int k0 = 0; k0 < 64; k0 += 32) {
#pragma unroll
        for (int c = 0; c < 2; ++c) {
            int r = wave * 32 + c * 16 + rl;
            int g = gpos ^ ((r >> 1) & 3);
            size_t gofs = (size_t)(row0 + r) * 256 + hd * 64 + k0 + g * 8;
            size_t lofs = (size_t)r * 32 + (size_t)gpos * 8;
            GLL16(xaggHi + gofs, &sA[0][lofs]);
            GLL16(xaggLo + gofs, &sA[1][lofs]);
        }
#pragma unroll
        for (int c = 0; c < 4; ++c) {
            int r = wave * 64 + c * 16 + rl;
            int g = gpos ^ ((r >> 1) & 3);
            size_t gofs = (size_t)(hd * 350 + col0 + r) * KP1 + k0 + g * 8;
            size_t lofs = (size_t)r * 32 + (size_t)gpos * 8;
            GLL16(w1Hi + gofs, &sB[0][lofs]);
            GLL16(w1Lo + gofs, &sB[1][lofs]);
        }
        __syncthreads();

        short8 ah[4], al[4], bh[8], bl[8];
#pragma unroll
        for (int j = 0; j < 8; j++) {
            int rb = wn + j * 16 + fr;
            bh[j] = *(const short8*)&sB[0][rb * 32 + gsw * 8];
            bl[j] = *(const short8*)&sB[1][rb * 32 + gsw * 8];
        }
#pragma unroll
        for (int i = 0; i < 4; i++) {
            int ra = wm + i * 16 + fr;
            ah[i] = *(const short8*)&sA[0][ra * 32 + gsw * 8];
            al[i] = *(const short8*)&sA[1][ra * 32 + gsw * 8];
        }
#pragma unroll
        for (int i = 0; i < 4; i++)
#pragma unroll
            for (int j = 0; j < 8; j++) {
                acc[i][j] = __builtin_amdgcn_mfma_f32_16x16x32_bf16(ah[i], bh[j],
                                                                   acc[i][j], 0, 0, 0);
                acc[i][j] = __builtin_amdgcn_mfma_f32_16x16x32_bf16(al[i], bh[j],
                                                                   acc[i][j], 0, 0, 0);
                acc[i][j] = __builtin_amdgcn_mfma_f32_16x16x32_bf16(ah[i], bl[j],
                                                                   acc[i][j], 0, 0, 0);
            }
        __syncthreads();
    }

#pragma unroll
    for (int i = 0; i < 4; i++) {
#pragma unroll
        for (int rg = 0; rg < 4; rg++) {
            int rr = row0 + wm + i * 16 + kq * 4 + rg;
            if (rr >= NNODES) continue;
#pragma unroll
            for (int j = 0; j < 8; j++) {
                int cc = col0 + wn + j * 16 + fr;
                if (cc < 350) {
                    int gc = hd * 350 + cc;
                    float v = acc[i][j][rg] + bias[gc];
                    v = v > 0.f ? v : expm1f(v);
                    unsigned short hi = f2bf(v);
                    actHi[(size_t)rr * KP2 + gc] = hi;
                    actLo[(size_t)rr * KP2 + gc] = f2bf(v - bf2f(hi));
                }
            }
        }
    }
}

// ---------------- alpha from act (hi/lo planes): a[n,h] = act . at[h,:] ------
__global__ __launch_bounds__(256) void alpha_act(
    const unsigned short* __restrict__ actHi, const unsigned short* __restrict__ actLo,
    const float* __restrict__ ats, const float* __restrict__ atd,
    float* __restrict__ asx, float* __restrict__ adx) {
    int wave = threadIdx.x >> 6, lane = threadIdx.x & 63;
    int n = blockIdx.x * 4 + wave;
    if (n >= NNODES) return;
    float p[8] = {0.f, 0.f, 0.f, 0.f, 0.f, 0.f, 0.f, 0.f};
    for (int k = lane; k < 1400; k += 64) {
        float v = bf2f(actHi[(size_t)n * KP2 + k]) + bf2f(actLo[(size_t)n * KP2 + k]);
#pragma unroll
        for (int h = 0; h < 4; h++) {
            p[h] = fmaf(v, ats[h * 1400 + k], p[h]);
            p[4 + h] = fmaf(v, atd[h * 1400 + k], p[4 + h]);
        }
    }
#pragma unroll
    for (int q = 0; q < 8; q++)
#pragma unroll
        for (int o = 32; o > 0; o >>= 1) p[q] += __shfl_xor(p[q], o, 64);
    if (lane == 0) {
#pragma unroll
        for (int h = 0; h < 4; h++) {
            asx[n * 4 + h] = p[h];
            adx[n * 4 + h] = p[4 + h];
        }
    }
}

// ---------------- 2-product split GEMM: C = (Ahi+Alo) @ Bhi^T, 128x256 tile ---
__global__ __launch_bounds__(256, 2) void gemm_hilo2(
    const unsigned short* __restrict__ Ahi, const unsigned short* __restrict__ Alo,
    const unsigned short* __restrict__ Bhi, float* __restrict__ C, int NN, int M,
    int Kp, int ldc) {
    __shared__ __align__(16) unsigned short sA[2][128 * 32];
    __shared__ __align__(16) unsigned short sB[256 * 32];
    int tid = threadIdx.x;
    int wave = tid >> 6, lane = tid & 63;
    int wm = (wave >> 1) * 64, wn = (wave & 1) * 128;
    int fr = lane & 15, kq = lane >> 4;
    int row0 = blockIdx.y * 128, col0 = blockIdx.x * 256;

    floatx4 acc[4][8];
#pragma unroll
    for (int i = 0; i < 4; i++)
#pragma unroll
        for (int j = 0; j < 8; j++)
#pragma unroll
            for (int q = 0; q < 4; q++) acc[i][j][q] = 0.f;

    int gpos = lane & 3;
    int rl = lane >> 2;
    int gsw = kq ^ ((fr >> 1) & 3);

    for (int k0 = 0; k0 < Kp; k0 += 32) {
#pragma unroll
        for (int c = 0; c < 2; ++c) {
            int r = wave * 32 + c * 16 + rl;
            int g = gpos ^ ((r >> 1) & 3);
            size_t gofs = (size_t)(row0 + r) * Kp + k0 + g * 8;
            size_t lofs = (size_t)r * 32 + (size_t)gpos * 8;
            GLL16(Ahi + gofs, &sA[0][lofs]);
            GLL16(Alo + gofs, &sA[1][lofs]);
        }
#pragma unroll
        for (int c = 0; c < 4; ++c) {
            int r = wave * 64 + c * 16 + rl;
            int g = gpos ^ ((r >> 1) & 3);
            size_t gofs = (size_t)(col0 + r) * Kp + k0 + g * 8;
            size_t lofs = (size_t)r * 32 + (size_t)gpos * 8;
            GLL16(Bhi + gofs, &sB[lofs]);
        }
        __syncthreads();

        short8 ah[4], al[4], bh[8];
#pragma unroll
        for (int j = 0; j < 8; j++) {
            int rb = wn + j * 16 + fr;
            bh[j] = *(const short8*)&sB[rb * 32 + gsw * 8];
        }
#pragma unroll
        for (int i = 0; i < 4; i++) {
            int ra = wm + i * 16 + fr;
            ah[i] = *(const short8*)&sA[0][ra * 32 + gsw * 8];
            al[i] = *(const short8*)&sA[1][ra * 32 + gsw * 8];
        }
#pragma unroll
        for (int i = 0; i < 4; i++)
#pragma unroll
            for (int j = 0; j < 8; j++) {
                acc[i][j] = __builtin_amdgcn_mfma_f32_16x16x32_bf16(ah[i], bh[j],
                                                                   acc[i][j], 0, 0, 0);
                acc[i][j] = __builtin_amdgcn_mfma_f32_16x16x32_bf16(al[i], bh[j],
                                                                   acc[i][j], 0, 0, 0);
            }
        __syncthreads();
    }

    // C/D layout: col=lane&15, row=(lane>>4)*4+reg
#pragma unroll
    for (int i = 0; i < 4; i++) {
#pragma unroll
        for (int rg = 0; rg < 4; rg++) {
            int rr = row0 + wm + i * 16 + kq * 4 + rg;
            if (rr >= NN) continue;
#pragma unroll
            for (int j = 0; j < 8; j++) {
                int cc = col0 + wn + j * 16 + fr;
                if (cc < M) C[(size_t)rr * ldc + cc] = acc[i][j][rg];
            }
        }
    }
}

// ---------------- softmax-weighted aggregation, one block per dst node -------
#define AGG_T 384
template <int H, int C, int MODE, int DOELU, int SKIP, int HN>
__global__ __launch_bounds__(AGG_T) void agg2(
    const float* __restrict__ hpre, int ldh, const float* __restrict__ skip,
    const float* __restrict__ as_n, const float* __restrict__ ad_n,
    const int* __restrict__ indptr, const int* __restrict__ esrc,
    const float* __restrict__ bias, unsigned short* __restrict__ outHi,
    unsigned short* __restrict__ outLo, int Kp, float* __restrict__ outF,
    const float* __restrict__ atns, const float* __restrict__ atnd,
    float* __restrict__ asx, float* __restrict__ adx) {
    constexpr int HC = H * C;
    int n = blockIdx.x;
    int tid = threadIdx.x;
    int s = indptr[n], e = indptr[n + 1];
    int deg = e - s;
    if (deg > MAXE) deg = MAXE;

    __shared__ int srcs[MAXE];
    __shared__ float wgt[MAXE * H];
    __shared__ float aggsh[MODE ? HC : 1];
    __shared__ float sAl[16];
    if (tid < 16) sAl[tid] = 0.f;

    if (tid < 64) {
        int lane = tid;
        float adv[H], mx[H], sm[H];
#pragma unroll
        for (int h = 0; h < H; h++) {
            adv[h] = ad_n[n * H + h];
            mx[h] = -1e30f;
            sm[h] = 0.f;
        }
        for (int j = lane; j < deg; j += 64) {
            int sr = esrc[s + j];
            srcs[j] = sr;
#pragma unroll
            for (int h = 0; h < H; h++) {
                float ev = as_n[sr * H + h] + adv[h];
                ev = ev > 0.f ? ev : 0.2f * ev;
                wgt[j * H + h] = ev;
                mx[h] = fmaxf(mx[h], ev);
            }
        }
#pragma unroll
        for (int h = 0; h < H; h++)
#pragma unroll
            for (int o = 32; o > 0; o >>= 1) mx[h] = fmaxf(mx[h], __shfl_xor(mx[h], o, 64));
        for (int j = lane; j < deg; j += 64) {
#pragma unroll
            for (int h = 0; h < H; h++) {
                float p = __expf(wgt[j * H + h] - mx[h]);
                wgt[j * H + h] = p;
                sm[h] += p;
            }
        }
#pragma unroll
        for (int h = 0; h < H; h++) {
#pragma unroll
            for (int o = 32; o > 0; o >>= 1) sm[h] += __shfl_xor(sm[h], o, 64);
            sm[h] = 1.f / sm[h];
        }
        for (int j = lane; j < deg; j += 64) {
#pragma unroll
            for (int h = 0; h < H; h++) wgt[j * H + h] *= sm[h];
        }
    }
    __syncthreads();

    if (MODE == 0) {
        constexpr int NV4 = HC / 4;
        constexpr int NP = (HN > 0) ? 2 * HN : 1;
        float p[NP];
#pragma unroll
        for (int q = 0; q < NP; q++) p[q] = 0.f;

        for (int c4 = tid; c4 < NV4; c4 += AGG_T) {
            int cb = c4 * 4;
            int h0 = (cb + 0) / C, h1 = (cb + 1) / C;
            int h2c = (cb + 2) / C, h3 = (cb + 3) / C;
            float ax = 0.f, ay = 0.f, az = 0.f, aw = 0.f;
            int j = 0;
            for (; j + 3 < deg; j += 4) {
                const float4 v0 = *(const float4*)(hpre + (size_t)srcs[j] * ldh + cb);
                const float4 v1 = *(const float4*)(hpre + (size_t)srcs[j + 1] * ldh + cb);
                const float4 v2 = *(const float4*)(hpre + (size_t)srcs[j + 2] * ldh + cb);
                const float4 v3 = *(const float4*)(hpre + (size_t)srcs[j + 3] * ldh + cb);
                const float* w0 = &wgt[j * H];
                const float* w1 = &wgt[(j + 1) * H];
                const float* w2 = &wgt[(j + 2) * H];
                const float* w3 = &wgt[(j + 3) * H];
                ax = fmaf(w0[h0], v0.x, ax); ay = fmaf(w0[h1], v0.y, ay);
                az = fmaf(w0[h2c], v0.z, az); aw = fmaf(w0[h3], v0.w, aw);
                ax = fmaf(w1[h0], v1.x, ax); ay = fmaf(w1[h1], v1.y, ay);
                az = fmaf(w1[h2c], v1.z, az); aw = fmaf(w1[h3], v1.w, aw);
                ax = fmaf(w2[h0], v2.x, ax); ay = fmaf(w2[h1], v2.y, ay);
                az = fmaf(w2[h2c], v2.z, az); aw = fmaf(w2[h3], v2.w, aw);
                ax = fmaf(w3[h0], v3.x, ax); ay = fmaf(w3[h1], v3.y, ay);
                az = fmaf(w3[h2c], v3.z, az); aw = fmaf(w3[h3], v3.w, aw);
            }
            for (; j < deg; j++) {
                const float4 v0 = *(const float4*)(hpre + (size_t)srcs[j] * ldh + cb);
                const float* w0 = &wgt[j * H];
                ax = fmaf(w0[h0], v0.x, ax); ay = fmaf(w0[h1], v0.y, ay);
                az = fmaf(w0[h2c], v0.z, az); aw = fmaf(w0[h3], v0.w, aw);
            }
            ax += bias[cb + 0];
            ay += bias[cb + 1];
            az += bias[cb + 2];
            aw += bias[cb + 3];
            if (DOELU) {
                ax = ax > 0.f ? ax : expm1f(ax);
                ay = ay > 0.f ? ay : expm1f(ay);
                az = az > 0.f ? az : expm1f(az);
                aw = aw > 0.f ? aw : expm1f(aw);
            }
            if (SKIP) {
                const float4 sk = *(const float4*)(skip + (size_t)n * ldh + cb);
                ax += sk.x;
                ay += sk.y;
                az += sk.z;
                aw += sk.w;
            }
            if (HN > 0) {
                float vq[4] = {ax, ay, az, aw};
#pragma unroll
                for (int h = 0; h < HN; h++) {
                    float ss = 0.f, dd = 0.f;
#pragma unroll
                    for (int q = 0; q < 4; q++) {
                        ss = fmaf(vq[q], atns[(size_t)h * HC + cb + q], ss);
                        dd = fmaf(vq[q], atnd[(size_t)h * HC + cb + q], dd);
                    }
                    p[h] += ss;
                    p[HN + h] += dd;
                }
            }
            ushort4 hi4, lo4;
            hi4.x = f2bf(ax); lo4.x = f2bf(ax - bf2f(hi4.x));
            hi4.y = f2bf(ay); lo4.y = f2bf(ay - bf2f(hi4.y));
            hi4.z = f2bf(az); lo4.z = f2bf(az - bf2f(hi4.z));
            hi4.w = f2bf(aw); lo4.w = f2bf(aw - bf2f(hi4.w));
            *(ushort4*)(outHi + (size_t)n * Kp + cb) = hi4;
            *(ushort4*)(outLo + (size_t)n * Kp + cb) = lo4;
        }
        for (int c = HC + tid; c < Kp; c += AGG_T) {
            outHi[(size_t)n * Kp + c] = 0;
            outLo[(size_t)n * Kp + c] = 0;
        }
        if (HN > 0) {
#pragma unroll
            for (int q = 0; q < NP; q++)
#pragma unroll
                for (int o = 32; o > 0; o >>= 1) p[q] += __shfl_xor(p[q], o, 64);
            if ((tid & 63) == 0) {
#pragma unroll
                for (int q = 0; q < NP; q++) atomicAdd(&sAl[q], p[q]);
            }
            __syncthreads();
            if (tid < HN) asx[n * HN + tid] = sAl[tid];
            else if (tid < 2 * HN) adx[n * HN + (tid - HN)] = sAl[tid];
        }
    } else {
        for (int cc = tid; cc < HC; cc += AGG_T) {
            int h = cc / C;
            float a = 0.f;
            for (int j = 0; j < deg; ++j)
                a = fmaf(wgt[j * H + h], hpre[(size_t)srcs[j] * ldh + cc], a);
            aggsh[cc] = a;
        }
        __syncthreads();
        for (int c = tid; c < C; c += AGG_T) {
            float sres = 0.f;
#pragma unroll
            for (int h = 0; h < H; h++) sres += aggsh[h * C + c];
            outF[(size_t)n * C + c] = sres * (1.f / (float)H) + bias[c];
        }
    }
}

// ---------------- launcher ----------------
extern "C" void kernel_launch(void* const* d_in, const int* in_sizes, int n_in,
                              void* d_out, int out_size, void* d_ws, size_t ws_size,
                              hipStream_t stream) {
    const float* x = (const float*)d_in[0];
    const int* ei = (const int*)d_in[1];
    const float* W1 = (const float*)d_in[2];
    const float* a1s = (const float*)d_in[3];
    const float* a1d = (const float*)d_in[4];
    const float* b1 = (const float*)d_in[5];
    const float* W2 = (const float*)d_in[6];
    const float* a2s = (const float*)d_in[7];
    const float* a2d = (const float*)d_in[8];
    const float* b2 = (const float*)d_in[9];
    const float* Wsk = (const float*)d_in[10];
    const float* W3 = (const float*)d_in[11];
    const float* a3s = (const float*)d_in[12];
    const float* a3d = (const float*)d_in[13];
    const float* b3 = (const float*)d_in[14];
    float* out = (float*)d_out;

    char* w = (char*)d_ws;
    size_t off = 0;
    auto alloc = [&](size_t bytes) -> char* {
        char* p = w + off;
        off += (bytes + 255) & ~(size_t)255;
        return p;
    };
    float* hpre = (float*)alloc((size_t)NNODES * 2800 * 4);
    unsigned short* actHi = (unsigned short*)alloc((size_t)(NNODES + ROWSLACK) * KP2 * 2);
    unsigned short* actLo = (unsigned short*)alloc((size_t)(NNODES + ROWSLACK) * KP2 * 2);
    unsigned short* xaggHi = (unsigned short*)alloc((size_t)(NNODES + ROWSLACK) * 256 * 2);
    unsigned short* xaggLo = (unsigned short*)alloc((size_t)(NNODES + ROWSLACK) * 256 * 2);
    unsigned short* w1Hi = (unsigned short*)alloc((size_t)(1400 + 512) * KP1 * 2);
    unsigned short* w1Lo = (unsigned short*)alloc((size_t)(1400 + 512) * KP1 * 2);
    unsigned short* w2Hi = (unsigned short*)alloc((size_t)(2800 + ROWSLACK) * KP2 * 2);
    unsigned short* w3Hi = (unsigned short*)alloc((size_t)(726 + ROWSLACK) * KP2 * 2);
    // zero block: atall (28400 floats) + cnt (NNODES+16 ints), contiguous
    float* atall = (float*)alloc((size_t)28400 * 4);
    int* cnt = (int*)alloc((size_t)(NNODES + 16) * 4);
    float* at1s = atall;
    float* at1d = atall + 200;
    float* at2s = atall + 400;
    float* at2d = atall + 6000;
    float* at3s = atall + 11600;
    float* at3d = atall + 20000;
    float* asP = (float*)alloc((size_t)NNODES * 6 * 4);
    float* adP = (float*)alloc((size_t)NNODES * 6 * 4);
    float* asQ = (float*)alloc((size_t)NNODES * 6 * 4);
    float* adQ = (float*)alloc((size_t)NNODES * 6 * 4);
    int* indptr = (int*)alloc((size_t)(NNODES + 16) * 4);
    int* cursor = (int*)alloc((size_t)(NNODES + 16) * 4);
    int* esrc = (int*)alloc((size_t)E2 * 4);

    // ---- one memset for atomic-accumulated + counter buffers ----
    size_t zbytes = (size_t)((char*)cnt - (char*)atall) + (NNODES + 16) * 4;
    hipMemsetAsync(atall, 0, zbytes, stream);

    // ---- weight hi/lo splits + a-tilde precompute ----
    splitW1_kernel<<<1400, 64, 0, stream>>>(W1, w1Hi, w1Lo);
    splitB_kernel<<<dim3(6, 2800 + 726), 256, 0, stream>>>(W2, Wsk, W3, w2Hi, w3Hi);
    atil_kernel<<<dim3(1, 4, 5), 64, 0, stream>>>(W1, a1s, a1d, at1s, at1d, HIDC, F_IN, 70);
    atil_kernel<<<dim3(22, 4, 5), 64, 0, stream>>>(W2, a2s, a2d, at2s, at2d, HIDC, 1400, 70);
    atil_kernel<<<dim3(22, 6, 4), 64, 0, stream>>>(W3, a3s, a3d, at3s, at3d, OUTC, 1400, 31);
    alpha1x_kernel<<<(NNODES + 3) / 4, 256, 0, stream>>>(x, at1s, at1d, asP, adP);

    // ---- CSR build ----
    count_kernel<<<(E2 + 255) / 256, 256, 0, stream>>>(ei, cnt);
    scan_kernel<<<1, 1024, 0, stream>>>(cnt, indptr, cursor);
    scatter_kernel<<<(E2 + 255) / 256, 256, 0, stream>>>(ei, cursor, esrc);

    // ---- zero act K-pad columns (act1 path writes only cols 0..1399) ----
    zeropad_kernel<<<(NNODES * 8 + 255) / 256, 256, 0, stream>>>(actHi, actLo);

    dim3 blk(256);
    int gy = (NNODES + 127) / 128;  // 79

    // ---- Layer 1: aggregate-first ----
    agg_x<<<NNODES, 256, 0, stream>>>(x, asP, adP, indptr, esrc, xaggHi, xaggLo);
    gemm_h1<<<dim3(2, gy, 4), blk, 0, stream>>>(xaggHi, xaggLo, w1Hi, w1Lo, b1,
                                                actHi, actLo);
    alpha_act<<<(NNODES + 3) / 4, 256, 0, stream>>>(actHi, actLo, at2s, at2d, asQ, adQ);

    // ---- Layer 2 (fused with skip: B = [W2; Wskip], M = 2800, 2-product) ----
    {
        int HC = NH2 * HIDC;  // 1400
        int M = 2 * HC;       // 2800
        dim3 grid((M + 255) / 256, gy);
        gemm_hilo2<<<grid, blk, 0, stream>>>(actHi, actLo, w2Hi, hpre, NNODES, M, KP2, M);
        // agg reads alpha2 (Q), writes act2 + alpha3 (P)
        agg2<NH2, HIDC, 0, 1, 1, 6><<<NNODES, AGG_T, 0, stream>>>(
            hpre, M, hpre + HC, asQ, adQ, indptr, esrc, b2, actHi, actLo, KP2, nullptr,
            at3s, at3d, asP, adP);
    }
    // ---- Layer 3 (2-product) ----
    {
        int M = NH3 * OUTC;  // 726
        dim3 grid((M + 255) / 256, gy);
        gemm_hilo2<<<grid, blk, 0, stream>>>(actHi, actLo, w3Hi, hpre, NNODES, M, KP2, M);
        agg2<NH3, OUTC, 1, 0, 0, 0><<<NNODES, AGG_T, 0, stream>>>(
            hpre, M, nullptr, asP, adP, indptr, esrc, b3, nullptr, nullptr, 0, out,
            nullptr, nullptr, nullptr, nullptr);
    }
}

// Round 8
// 725.406 us; speedup vs baseline: 1.2461x; 1.1042x over previous
//
#include <hip/hip_runtime.h>
#include <math.h>

#define NNODES 10000
#define NEDGES 160000
#define E2 (NEDGES + NNODES)
#define F_IN 50
#define HIDC 350
#define NH1 4
#define NH2 4
#define NH3 6
#define OUTC 121
#define MAXE 512
#define KP1 64      // F_IN=50 padded to 64
#define KP2 1408    // 1400 padded to 1408
#define LD3 736     // layer-3 hpre row stride (726 padded to 16B multiple)
#define ROWSLACK 128

typedef __attribute__((ext_vector_type(8))) short short8;
typedef __attribute__((ext_vector_type(8))) unsigned short ushort8v;
typedef __attribute__((ext_vector_type(4))) float floatx4;

static __device__ __forceinline__ unsigned short f2bf(float f) {
    unsigned u = __float_as_uint(f);
    unsigned r = (u + 0x7fffu + ((u >> 16) & 1u)) >> 16;
    return (unsigned short)r;
}
static __device__ __forceinline__ float bf2f(unsigned short s) {
    return __uint_as_float(((unsigned)s) << 16);
}

// async global->LDS, 16 bytes per lane; LDS dest is wave-uniform base + lane*16
#define GLL16(gp, lp)                                                      \
    __builtin_amdgcn_global_load_lds(                                      \
        (const __attribute__((address_space(1))) void*)(gp),               \
        (__attribute__((address_space(3))) void*)(lp), 16, 0, 0)

// ---------------- CSR build (dst-sorted incoming edge lists) ----------------
__global__ void count_kernel(const int* __restrict__ ei, int* __restrict__ cnt) {
    int i = blockIdx.x * blockDim.x + threadIdx.x;
    if (i >= E2) return;
    int dst = (i < NEDGES) ? ei[NEDGES + i] : (i - NEDGES);
    atomicAdd(&cnt[dst], 1);
}

__global__ void scan_kernel(const int* __restrict__ cnt, int* __restrict__ indptr,
                            int* __restrict__ cursor) {
    __shared__ int part[1024];
    int tid = threadIdx.x;
    const int CH = (NNODES + 1023) / 1024;
    int base = tid * CH;
    int s = 0;
    for (int i = 0; i < CH; i++) {
        int idx = base + i;
        if (idx < NNODES) s += cnt[idx];
    }
    part[tid] = s;
    __syncthreads();
    for (int off = 1; off < 1024; off <<= 1) {
        int v = (tid >= off) ? part[tid - off] : 0;
        __syncthreads();
        part[tid] += v;
        __syncthreads();
    }
    int run = (tid == 0) ? 0 : part[tid - 1];
    for (int i = 0; i < CH; i++) {
        int idx = base + i;
        if (idx < NNODES) {
            indptr[idx] = run;
            cursor[idx] = run;
            run += cnt[idx];
        }
    }
    if (tid == 0) indptr[NNODES] = part[1023];
}

__global__ void scatter_kernel(const int* __restrict__ ei, int* __restrict__ cursor,
                               int* __restrict__ esrc) {
    int i = blockIdx.x * blockDim.x + threadIdx.x;
    if (i >= E2) return;
    int src, dst;
    if (i < NEDGES) {
        src = ei[i];
        dst = ei[NEDGES + i];
    } else {
        src = dst = i - NEDGES;
    }
    int pos = atomicAdd(&cursor[dst], 1);
    esrc[pos] = src;
}

// ---------------- fp32 -> bf16 hi/lo splits ----------------
__global__ void splitW1_kernel(const float* __restrict__ W1,
                               unsigned short* __restrict__ w1Hi,
                               unsigned short* __restrict__ w1Lo) {
    int k = threadIdx.x;  // 0..63
    int r = blockIdx.x;   // 0..1399
    float v = (k < F_IN) ? W1[(size_t)r * F_IN + k] : 0.f;
    unsigned short h = f2bf(v);
    w1Hi[(size_t)r * KP1 + k] = h;
    w1Lo[(size_t)r * KP1 + k] = f2bf(v - bf2f(h));
}

// hi-only split for W2/Wskip/W3 (2-product GEMM drops B-lo)
__global__ void splitB_kernel(const float* __restrict__ W2, const float* __restrict__ Wsk,
                              const float* __restrict__ W3,
                              unsigned short* __restrict__ w2Hi,
                              unsigned short* __restrict__ w3Hi) {
    int k = blockIdx.x * blockDim.x + threadIdx.x;
    if (k >= KP2) return;
    int r = blockIdx.y;
    const int K = 1400;
    const float* src;
    unsigned short* hi;
    int row;
    if (r < 1400) { src = W2; row = r; hi = w2Hi; }
    else if (r < 2800) { src = Wsk; row = r - 1400; hi = w2Hi + (size_t)1400 * KP2; }
    else { src = W3; row = r - 2800; hi = w3Hi; }
    float v = (k < K) ? src[(size_t)row * K + k] : 0.f;
    hi[(size_t)row * KP2 + k] = f2bf(v);
}

// ---------------- a-tilde precompute: at[h][k] = sum_c W[h*C+c, k] * a[h,c] ----
__global__ void atil_kernel(const float* __restrict__ W, const float* __restrict__ av_s,
                            const float* __restrict__ av_d, float* __restrict__ outS,
                            float* __restrict__ outD, int C, int K, int cchunk) {
    int k = blockIdx.x * 64 + (threadIdx.x & 63);
    if (k >= K) return;
    int h = blockIdx.y;
    int c0 = blockIdx.z * cchunk;
    int c1 = c0 + cchunk;
    if (c1 > C) c1 = C;
    float ss = 0.f, dd = 0.f;
    for (int c = c0; c < c1; c++) {
        float wv = W[((size_t)h * C + c) * K + k];
        ss = fmaf(wv, av_s[h * C + c], ss);
        dd = fmaf(wv, av_d[h * C + c], dd);
    }
    atomicAdd(&outS[(size_t)h * K + k], ss);
    atomicAdd(&outD[(size_t)h * K + k], dd);
}

// ---------------- layer-1 alpha directly from x ----------------
__global__ __launch_bounds__(256) void alpha1x_kernel(const float* __restrict__ x,
                                                      const float* __restrict__ at1s,
                                                      const float* __restrict__ at1d,
                                                      float* __restrict__ as1,
                                                      float* __restrict__ ad1) {
    int wave = threadIdx.x >> 6, lane = threadIdx.x & 63;
    int n = blockIdx.x * 4 + wave;
    if (n >= NNODES) return;
    int kk = lane < F_IN ? lane : F_IN - 1;
    float v = (lane < F_IN) ? x[(size_t)n * F_IN + lane] : 0.f;
    float p[8];
#pragma unroll
    for (int h = 0; h < 4; h++) {
        p[h] = v * at1s[h * F_IN + kk];
        p[4 + h] = v * at1d[h * F_IN + kk];
    }
#pragma unroll
    for (int s = 0; s < 8; s++)
#pragma unroll
        for (int o = 32; o > 0; o >>= 1) p[s] += __shfl_xor(p[s], o, 64);
    if (lane == 0) {
#pragma unroll
        for (int h = 0; h < 4; h++) {
            as1[n * 4 + h] = p[h];
            ad1[n * 4 + h] = p[4 + h];
        }
    }
}

// ---------------- zero the K-pad columns of act (cols 1400..1407) -----------
__global__ void zeropad_kernel(unsigned short* __restrict__ hi,
                               unsigned short* __restrict__ lo) {
    int i = blockIdx.x * 256 + threadIdx.x;
    if (i >= NNODES * 8) return;
    int n = i >> 3, c = 1400 + (i & 7);
    hi[(size_t)n * KP2 + c] = 0;
    lo[(size_t)n * KP2 + c] = 0;
}

// ---------------- layer-1 aggregate-first: xagg[n, h*64+k] = sum_j a_jh x_j[k]
__global__ __launch_bounds__(256) void agg_x(
    const float* __restrict__ x, const float* __restrict__ as_n,
    const float* __restrict__ ad_n, const int* __restrict__ indptr,
    const int* __restrict__ esrc, unsigned short* __restrict__ xaggHi,
    unsigned short* __restrict__ xaggLo) {
    int n = blockIdx.x, tid = threadIdx.x;
    int s = indptr[n], e = indptr[n + 1];
    int deg = e - s;
    if (deg > MAXE) deg = MAXE;
    __shared__ int srcs[MAXE];
    __shared__ float wgt[MAXE * 4];

    if (tid < 64) {
        int lane = tid;
        float adv[4], mx[4], sm[4];
#pragma unroll
        for (int h = 0; h < 4; h++) {
            adv[h] = ad_n[n * 4 + h];
            mx[h] = -1e30f;
            sm[h] = 0.f;
        }
        for (int j = lane; j < deg; j += 64) {
            int sr = esrc[s + j];
            srcs[j] = sr;
#pragma unroll
            for (int h = 0; h < 4; h++) {
                float ev = as_n[sr * 4 + h] + adv[h];
                ev = ev > 0.f ? ev : 0.2f * ev;
                wgt[j * 4 + h] = ev;
                mx[h] = fmaxf(mx[h], ev);
            }
        }
#pragma unroll
        for (int h = 0; h < 4; h++)
#pragma unroll
            for (int o = 32; o > 0; o >>= 1) mx[h] = fmaxf(mx[h], __shfl_xor(mx[h], o, 64));
        for (int j = lane; j < deg; j += 64) {
#pragma unroll
            for (int h = 0; h < 4; h++) {
                float p = __expf(wgt[j * 4 + h] - mx[h]);
                wgt[j * 4 + h] = p;
                sm[h] += p;
            }
        }
#pragma unroll
        for (int h = 0; h < 4; h++) {
#pragma unroll
            for (int o = 32; o > 0; o >>= 1) sm[h] += __shfl_xor(sm[h], o, 64);
            sm[h] = 1.f / sm[h];
        }
        for (int j = lane; j < deg; j += 64) {
#pragma unroll
            for (int h = 0; h < 4; h++) wgt[j * 4 + h] *= sm[h];
        }
    }
    __syncthreads();

    int h = tid >> 6, k = tid & 63;
    float a = 0.f;
    if (k < F_IN) {
        int j = 0;
        float a2 = 0.f;
        for (; j + 1 < deg; j += 2) {
            a = fmaf(wgt[j * 4 + h], x[(size_t)srcs[j] * F_IN + k], a);
            a2 = fmaf(wgt[(j + 1) * 4 + h], x[(size_t)srcs[j + 1] * F_IN + k], a2);
        }
        if (j < deg) a = fmaf(wgt[j * 4 + h], x[(size_t)srcs[j] * F_IN + k], a);
        a += a2;
    }
    unsigned short hi = f2bf(a);
    xaggHi[(size_t)n * 256 + tid] = hi;
    xaggLo[(size_t)n * 256 + tid] = f2bf(a - bf2f(hi));  // k>=F_IN lanes write 0 (K-pad)
}

// ---------------- layer-1 per-head GEMM: act1 = ELU(W1_h . xagg_h + b1) -------
// full 3-product split (layer-1 accuracy feeds everything downstream)
__global__ __launch_bounds__(256, 2) void gemm_h1(
    const unsigned short* __restrict__ xaggHi, const unsigned short* __restrict__ xaggLo,
    const unsigned short* __restrict__ w1Hi, const unsigned short* __restrict__ w1Lo,
    const float* __restrict__ bias, unsigned short* __restrict__ actHi,
    unsigned short* __restrict__ actLo) {
    __shared__ __align__(16) unsigned short sA[2][128 * 32];
    __shared__ __align__(16) unsigned short sB[2][256 * 32];
    int tid = threadIdx.x;
    int wave = tid >> 6, lane = tid & 63;
    int wm = (wave >> 1) * 64, wn = (wave & 1) * 128;
    int fr = lane & 15, kq = lane >> 4;
    int row0 = blockIdx.y * 128, col0 = blockIdx.x * 256;
    int hd = blockIdx.z;

    floatx4 acc[4][8];
#pragma unroll
    for (int i = 0; i < 4; i++)
#pragma unroll
        for (int j = 0; j < 8; j++)
#pragma unroll
            for (int q = 0; q < 4; q++) acc[i][j][q] = 0.f;

    int gpos = lane & 3;
    int rl = lane >> 2;
    int gsw = kq ^ ((fr >> 1) & 3);

    for (int k0 = 0; k0 < 64; k0 += 32) {
#pragma unroll
        for (int c = 0; c < 2; ++c) {
            int r = wave * 32 + c * 16 + rl;
            int g = gpos ^ ((r >> 1) & 3);
            size_t gofs = (size_t)(row0 + r) * 256 + hd * 64 + k0 + g * 8;
            size_t lofs = (size_t)r * 32 + (size_t)gpos * 8;
            GLL16(xaggHi + gofs, &sA[0][lofs]);
            GLL16(xaggLo + gofs, &sA[1][lofs]);
        }
#pragma unroll
        for (int c = 0; c < 4; ++c) {
            int r = wave * 64 + c * 16 + rl;
            int g = gpos ^ ((r >> 1) & 3);
            size_t gofs = (size_t)(hd * 350 + col0 + r) * KP1 + k0 + g * 8;
            size_t lofs = (size_t)r * 32 + (size_t)gpos * 8;
            GLL16(w1Hi + gofs, &sB[0][lofs]);
            GLL16(w1Lo + gofs, &sB[1][lofs]);
        }
        __syncthreads();

        short8 ah[4], al[4], bh[8], bl[8];
#pragma unroll
        for (int j = 0; j < 8; j++) {
            int rb = wn + j * 16 + fr;
            bh[j] = *(const short8*)&sB[0][rb * 32 + gsw * 8];
            bl[j] = *(const short8*)&sB[1][rb * 32 + gsw * 8];
        }
#pragma unroll
        for (int i = 0; i < 4; i++) {
            int ra = wm + i * 16 + fr;
            ah[i] = *(const short8*)&sA[0][ra * 32 + gsw * 8];
            al[i] = *(const short8*)&sA[1][ra * 32 + gsw * 8];
        }
#pragma unroll
        for (int i = 0; i < 4; i++)
#pragma unroll
            for (int j = 0; j < 8; j++) {
                acc[i][j] = __builtin_amdgcn_mfma_f32_16x16x32_bf16(ah[i], bh[j],
                                                                   acc[i][j], 0, 0, 0);
                acc[i][j] = __builtin_amdgcn_mfma_f32_16x16x32_bf16(al[i], bh[j],
                                                                   acc[i][j], 0, 0, 0);
                acc[i][j] = __builtin_amdgcn_mfma_f32_16x16x32_bf16(ah[i], bl[j],
                                                                   acc[i][j], 0, 0, 0);
            }
        __syncthreads();
    }

#pragma unroll
    for (int i = 0; i < 4; i++) {
#pragma unroll
        for (int rg = 0; rg < 4; rg++) {
            int rr = row0 + wm + i * 16 + kq * 4 + rg;
            if (rr >= NNODES) continue;
#pragma unroll
            for (int j = 0; j < 8; j++) {
                int cc = col0 + wn + j * 16 + fr;
                if (cc < 350) {
                    int gc = hd * 350 + cc;
                    float v = acc[i][j][rg] + bias[gc];
                    v = v > 0.f ? v : expm1f(v);
                    unsigned short hi = f2bf(v);
                    actHi[(size_t)rr * KP2 + gc] = hi;
                    actLo[(size_t)rr * KP2 + gc] = f2bf(v - bf2f(hi));
                }
            }
        }
    }
}

// ---------------- alpha from act (hi/lo planes): a[n,h] = act . at[h,:] ------
__global__ __launch_bounds__(256) void alpha_act(
    const unsigned short* __restrict__ actHi, const unsigned short* __restrict__ actLo,
    const float* __restrict__ ats, const float* __restrict__ atd,
    float* __restrict__ asx, float* __restrict__ adx) {
    int wave = threadIdx.x >> 6, lane = threadIdx.x & 63;
    int n = blockIdx.x * 4 + wave;
    if (n >= NNODES) return;
    float p[8] = {0.f, 0.f, 0.f, 0.f, 0.f, 0.f, 0.f, 0.f};
    for (int k = lane; k < 1400; k += 64) {
        float v = bf2f(actHi[(size_t)n * KP2 + k]) + bf2f(actLo[(size_t)n * KP2 + k]);
#pragma unroll
        for (int h = 0; h < 4; h++) {
            p[h] = fmaf(v, ats[h * 1400 + k], p[h]);
            p[4 + h] = fmaf(v, atd[h * 1400 + k], p[4 + h]);
        }
    }
#pragma unroll
    for (int q = 0; q < 8; q++)
#pragma unroll
        for (int o = 32; o > 0; o >>= 1) p[q] += __shfl_xor(p[q], o, 64);
    if (lane == 0) {
#pragma unroll
        for (int h = 0; h < 4; h++) {
            asx[n * 4 + h] = p[h];
            adx[n * 4 + h] = p[4 + h];
        }
    }
}

// ---------------- 2-product split GEMM, bf16 output, 128x256 tile -------------
// C[rr,cc] (bf16) = (Ahi+Alo) @ Bhi^T; A-lo product applied only to columns
// whose 16-wide subtile starts below LOLIM (skip-connection columns use 1-product).
__global__ __launch_bounds__(256, 2) void gemm_hilo2(
    const unsigned short* __restrict__ Ahi, const unsigned short* __restrict__ Alo,
    const unsigned short* __restrict__ Bhi, unsigned short* __restrict__ Cb, int NN,
    int M, int Kp, int ldc, int LOLIM) {
    __shared__ __align__(16) unsigned short sA[2][128 * 32];
    __shared__ __align__(16) unsigned short sB[256 * 32];
    int tid = threadIdx.x;
    int wave = tid >> 6, lane = tid & 63;
    int wm = (wave >> 1) * 64, wn = (wave & 1) * 128;
    int fr = lane & 15, kq = lane >> 4;
    int row0 = blockIdx.y * 128, col0 = blockIdx.x * 256;

    floatx4 acc[4][8];
#pragma unroll
    for (int i = 0; i < 4; i++)
#pragma unroll
        for (int j = 0; j < 8; j++)
#pragma unroll
            for (int q = 0; q < 4; q++) acc[i][j][q] = 0.f;

    int gpos = lane & 3;
    int rl = lane >> 2;
    int gsw = kq ^ ((fr >> 1) & 3);

    for (int k0 = 0; k0 < Kp; k0 += 32) {
#pragma unroll
        for (int c = 0; c < 2; ++c) {
            int r = wave * 32 + c * 16 + rl;
            int g = gpos ^ ((r >> 1) & 3);
            size_t gofs = (size_t)(row0 + r) * Kp + k0 + g * 8;
            size_t lofs = (size_t)r * 32 + (size_t)gpos * 8;
            GLL16(Ahi + gofs, &sA[0][lofs]);
            GLL16(Alo + gofs, &sA[1][lofs]);
        }
#pragma unroll
        for (int c = 0; c < 4; ++c) {
            int r = wave * 64 + c * 16 + rl;
            int g = gpos ^ ((r >> 1) & 3);
            size_t gofs = (size_t)(col0 + r) * Kp + k0 + g * 8;
            size_t lofs = (size_t)r * 32 + (size_t)gpos * 8;
            GLL16(Bhi + gofs, &sB[lofs]);
        }
        __syncthreads();

        short8 ah[4], al[4], bh[8];
#pragma unroll
        for (int j = 0; j < 8; j++) {
            int rb = wn + j * 16 + fr;
            bh[j] = *(const short8*)&sB[rb * 32 + gsw * 8];
        }
#pragma unroll
        for (int i = 0; i < 4; i++) {
            int ra = wm + i * 16 + fr;
            ah[i] = *(const short8*)&sA[0][ra * 32 + gsw * 8];
            al[i] = *(const short8*)&sA[1][ra * 32 + gsw * 8];
        }
#pragma unroll
        for (int j = 0; j < 8; j++) {
            bool lo_on = (col0 + wn + j * 16) < LOLIM;
#pragma unroll
            for (int i = 0; i < 4; i++) {
                acc[i][j] = __builtin_amdgcn_mfma_f32_16x16x32_bf16(ah[i], bh[j],
                                                                   acc[i][j], 0, 0, 0);
                if (lo_on)
                    acc[i][j] = __builtin_amdgcn_mfma_f32_16x16x32_bf16(al[i], bh[j],
                                                                       acc[i][j], 0, 0, 0);
            }
        }
        __syncthreads();
    }

    // C/D layout: col=lane&15, row=(lane>>4)*4+reg
#pragma unroll
    for (int i = 0; i < 4; i++) {
#pragma unroll
        for (int rg = 0; rg < 4; rg++) {
            int rr = row0 + wm + i * 16 + kq * 4 + rg;
            if (rr >= NN) continue;
#pragma unroll
            for (int j = 0; j < 8; j++) {
                int cc = col0 + wn + j * 16 + fr;
                if (cc < M) Cb[(size_t)rr * ldc + cc] = f2bf(acc[i][j][rg]);
            }
        }
    }
}

// ---------------- softmax-weighted aggregation, one block per dst node -------
// hpre is bf16. MODE 0: act = agg+bias (+ELU)(+skip from hpre cols 1400+);
// emit hi/lo planes; HN>0: fused next-layer alpha. MODE 1: fp32 head-mean out.
#define AGG_T 256
template <int H, int C, int MODE, int DOELU, int SKIP, int HN>
__global__ __launch_bounds__(AGG_T) void agg2(
    const unsigned short* __restrict__ hpreb, int ldh,
    const float* __restrict__ as_n, const float* __restrict__ ad_n,
    const int* __restrict__ indptr, const int* __restrict__ esrc,
    const float* __restrict__ bias, unsigned short* __restrict__ outHi,
    unsigned short* __restrict__ outLo, int Kp, float* __restrict__ outF,
    const float* __restrict__ atns, const float* __restrict__ atnd,
    float* __restrict__ asx, float* __restrict__ adx) {
    constexpr int HC = H * C;
    int n = blockIdx.x;
    int tid = threadIdx.x;
    int s = indptr[n], e = indptr[n + 1];
    int deg = e - s;
    if (deg > MAXE) deg = MAXE;

    __shared__ int srcs[MAXE];
    __shared__ float wgt[MAXE * H];
    __shared__ float aggsh[MODE ? HC : 1];
    __shared__ float sAl[16];
    if (tid < 16) sAl[tid] = 0.f;

    if (tid < 64) {
        int lane = tid;
        float adv[H], mx[H], sm[H];
#pragma unroll
        for (int h = 0; h < H; h++) {
            adv[h] = ad_n[n * H + h];
            mx[h] = -1e30f;
            sm[h] = 0.f;
        }
        for (int j = lane; j < deg; j += 64) {
            int sr = esrc[s + j];
            srcs[j] = sr;
#pragma unroll
            for (int h = 0; h < H; h++) {
                float ev = as_n[sr * H + h] + adv[h];
                ev = ev > 0.f ? ev : 0.2f * ev;
                wgt[j * H + h] = ev;
                mx[h] = fmaxf(mx[h], ev);
            }
        }
#pragma unroll
        for (int h = 0; h < H; h++)
#pragma unroll
            for (int o = 32; o > 0; o >>= 1) mx[h] = fmaxf(mx[h], __shfl_xor(mx[h], o, 64));
        for (int j = lane; j < deg; j += 64) {
#pragma unroll
            for (int h = 0; h < H; h++) {
                float p = __expf(wgt[j * H + h] - mx[h]);
                wgt[j * H + h] = p;
                sm[h] += p;
            }
        }
#pragma unroll
        for (int h = 0; h < H; h++) {
#pragma unroll
            for (int o = 32; o > 0; o >>= 1) sm[h] += __shfl_xor(sm[h], o, 64);
            sm[h] = 1.f / sm[h];
        }
        for (int j = lane; j < deg; j += 64) {
#pragma unroll
            for (int h = 0; h < H; h++) wgt[j * H + h] *= sm[h];
        }
    }
    __syncthreads();

    if (MODE == 0) {
        constexpr int NV8 = HC / 8;  // 175 for HC=1400
        constexpr int NP = (HN > 0) ? 2 * HN : 1;
        float p[NP];
#pragma unroll
        for (int q = 0; q < NP; q++) p[q] = 0.f;

        for (int c8 = tid; c8 < NV8; c8 += AGG_T) {
            int cb = c8 * 8;
            int hh[8];
#pragma unroll
            for (int q = 0; q < 8; q++) hh[q] = (cb + q) / C;
            float av[8];
#pragma unroll
            for (int q = 0; q < 8; q++) av[q] = 0.f;
            int j = 0;
            for (; j + 1 < deg; j += 2) {
                const ushort8v v0 = *(const ushort8v*)(hpreb + (size_t)srcs[j] * ldh + cb);
                const ushort8v v1 = *(const ushort8v*)(hpreb + (size_t)srcs[j + 1] * ldh + cb);
                const float* w0 = &wgt[j * H];
                const float* w1 = &wgt[(j + 1) * H];
#pragma unroll
                for (int q = 0; q < 8; q++) av[q] = fmaf(w0[hh[q]], bf2f(v0[q]), av[q]);
#pragma unroll
                for (int q = 0; q < 8; q++) av[q] = fmaf(w1[hh[q]], bf2f(v1[q]), av[q]);
            }
            if (j < deg) {
                const ushort8v v0 = *(const ushort8v*)(hpreb + (size_t)srcs[j] * ldh + cb);
                const float* w0 = &wgt[j * H];
#pragma unroll
                for (int q = 0; q < 8; q++) av[q] = fmaf(w0[hh[q]], bf2f(v0[q]), av[q]);
            }
#pragma unroll
            for (int q = 0; q < 8; q++) av[q] += bias[cb + q];
            if (DOELU) {
#pragma unroll
                for (int q = 0; q < 8; q++) av[q] = av[q] > 0.f ? av[q] : expm1f(av[q]);
            }
            if (SKIP) {
                const ushort8v sk = *(const ushort8v*)(hpreb + (size_t)n * ldh + 1400 + cb);
#pragma unroll
                for (int q = 0; q < 8; q++) av[q] += bf2f(sk[q]);
            }
            if (HN > 0) {
#pragma unroll
                for (int h = 0; h < HN; h++) {
                    float ss = 0.f, dd = 0.f;
#pragma unroll
                    for (int q = 0; q < 8; q++) {
                        ss = fmaf(av[q], atns[(size_t)h * HC + cb + q], ss);
                        dd = fmaf(av[q], atnd[(size_t)h * HC + cb + q], dd);
                    }
                    p[h] += ss;
                    p[HN + h] += dd;
                }
            }
            ushort8v hi8, lo8;
#pragma unroll
            for (int q = 0; q < 8; q++) {
                hi8[q] = f2bf(av[q]);
                lo8[q] = f2bf(av[q] - bf2f(hi8[q]));
            }
            *(ushort8v*)(outHi + (size_t)n * Kp + cb) = hi8;
            *(ushort8v*)(outLo + (size_t)n * Kp + cb) = lo8;
        }
        for (int c = HC + tid; c < Kp; c += AGG_T) {
            outHi[(size_t)n * Kp + c] = 0;
            outLo[(size_t)n * Kp + c] = 0;
        }
        if (HN > 0) {
#pragma unroll
            for (int q = 0; q < NP; q++)
#pragma unroll
                for (int o = 32; o > 0; o >>= 1) p[q] += __shfl_xor(p[q], o, 64);
            if ((tid & 63) == 0) {
#pragma unroll
                for (int q = 0; q < NP; q++) atomicAdd(&sAl[q], p[q]);
            }
            __syncthreads();
            if (tid < HN) asx[n * HN + tid] = sAl[tid];
            else if (tid < 2 * HN) adx[n * HN + (tid - HN)] = sAl[tid];
        }
    } else {
        for (int cc = tid; cc < HC; cc += AGG_T) {
            int h = cc / C;
            float a = 0.f;
            for (int j = 0; j < deg; ++j)
                a = fmaf(wgt[j * H + h], bf2f(hpreb[(size_t)srcs[j] * ldh + cc]), a);
            aggsh[cc] = a;
        }
        __syncthreads();
        for (int c = tid; c < C; c += AGG_T) {
            float sres = 0.f;
#pragma unroll
            for (int h = 0; h < H; h++) sres += aggsh[h * C + c];
            outF[(size_t)n * C + c] = sres * (1.f / (float)H) + bias[c];
        }
    }
}

// ---------------- launcher ----------------
extern "C" void kernel_launch(void* const* d_in, const int* in_sizes, int n_in,
                              void* d_out, int out_size, void* d_ws, size_t ws_size,
                              hipStream_t stream) {
    const float* x = (const float*)d_in[0];
    const int* ei = (const int*)d_in[1];
    const float* W1 = (const float*)d_in[2];
    const float* a1s = (const float*)d_in[3];
    const float* a1d = (const float*)d_in[4];
    const float* b1 = (const float*)d_in[5];
    const float* W2 = (const float*)d_in[6];
    const float* a2s = (const float*)d_in[7];
    const float* a2d = (const float*)d_in[8];
    const float* b2 = (const float*)d_in[9];
    const float* Wsk = (const float*)d_in[10];
    const float* W3 = (const float*)d_in[11];
    const float* a3s = (const float*)d_in[12];
    const float* a3d = (const float*)d_in[13];
    const float* b3 = (const float*)d_in[14];
    float* out = (float*)d_out;

    char* w = (char*)d_ws;
    size_t off = 0;
    auto alloc = [&](size_t bytes) -> char* {
        char* p = w + off;
        off += (bytes + 255) & ~(size_t)255;
        return p;
    };
    unsigned short* hpreb = (unsigned short*)alloc((size_t)(NNODES + ROWSLACK) * 2800 * 2);
    unsigned short* actHi = (unsigned short*)alloc((size_t)(NNODES + ROWSLACK) * KP2 * 2);
    unsigned short* actLo = (unsigned short*)alloc((size_t)(NNODES + ROWSLACK) * KP2 * 2);
    unsigned short* xaggHi = (unsigned short*)alloc((size_t)(NNODES + ROWSLACK) * 256 * 2);
    unsigned short* xaggLo = (unsigned short*)alloc((size_t)(NNODES + ROWSLACK) * 256 * 2);
    unsigned short* w1Hi = (unsigned short*)alloc((size_t)(1400 + 512) * KP1 * 2);
    unsigned short* w1Lo = (unsigned short*)alloc((size_t)(1400 + 512) * KP1 * 2);
    unsigned short* w2Hi = (unsigned short*)alloc((size_t)(2800 + ROWSLACK) * KP2 * 2);
    unsigned short* w3Hi = (unsigned short*)alloc((size_t)(726 + ROWSLACK) * KP2 * 2);
    // zero block: atall (28400 floats) + cnt (NNODES+16 ints), contiguous
    float* atall = (float*)alloc((size_t)28400 * 4);
    int* cnt = (int*)alloc((size_t)(NNODES + 16) * 4);
    float* at1s = atall;
    float* at1d = atall + 200;
    float* at2s = atall + 400;
    float* at2d = atall + 6000;
    float* at3s = atall + 11600;
    float* at3d = atall + 20000;
    float* asP = (float*)alloc((size_t)NNODES * 6 * 4);
    float* adP = (float*)alloc((size_t)NNODES * 6 * 4);
    float* asQ = (float*)alloc((size_t)NNODES * 6 * 4);
    float* adQ = (float*)alloc((size_t)NNODES * 6 * 4);
    int* indptr = (int*)alloc((size_t)(NNODES + 16) * 4);
    int* cursor = (int*)alloc((size_t)(NNODES + 16) * 4);
    int* esrc = (int*)alloc((size_t)E2 * 4);

    // ---- one memset for atomic-accumulated + counter buffers ----
    size_t zbytes = (size_t)((char*)cnt - (char*)atall) + (NNODES + 16) * 4;
    hipMemsetAsync(atall, 0, zbytes, stream);

    // ---- weight hi/lo splits + a-tilde precompute ----
    splitW1_kernel<<<1400, 64, 0, stream>>>(W1, w1Hi, w1Lo);
    splitB_kernel<<<dim3(6, 2800 + 726), 256, 0, stream>>>(W2, Wsk, W3, w2Hi, w3Hi);
    atil_kernel<<<dim3(1, 4, 5), 64, 0, stream>>>(W1, a1s, a1d, at1s, at1d, HIDC, F_IN, 70);
    atil_kernel<<<dim3(22, 4, 5), 64, 0, stream>>>(W2, a2s, a2d, at2s, at2d, HIDC, 1400, 70);
    atil_kernel<<<dim3(22, 6, 4), 64, 0, stream>>>(W3, a3s, a3d, at3s, at3d, OUTC, 1400, 31);
    alpha1x_kernel<<<(NNODES + 3) / 4, 256, 0, stream>>>(x, at1s, at1d, asP, adP);

    // ---- CSR build ----
    count_kernel<<<(E2 + 255) / 256, 256, 0, stream>>>(ei, cnt);
    scan_kernel<<<1, 1024, 0, stream>>>(cnt, indptr, cursor);
    scatter_kernel<<<(E2 + 255) / 256, 256, 0, stream>>>(ei, cursor, esrc);

    // ---- zero act K-pad columns (act1 path writes only cols 0..1399) ----
    zeropad_kernel<<<(NNODES * 8 + 255) / 256, 256, 0, stream>>>(actHi, actLo);

    dim3 blk(256);
    int gy = (NNODES + 127) / 128;  // 79

    // ---- Layer 1: aggregate-first ----
    agg_x<<<NNODES, 256, 0, stream>>>(x, asP, adP, indptr, esrc, xaggHi, xaggLo);
    gemm_h1<<<dim3(2, gy, 4), blk, 0, stream>>>(xaggHi, xaggLo, w1Hi, w1Lo, b1,
                                                actHi, actLo);
    alpha_act<<<(NNODES + 3) / 4, 256, 0, stream>>>(actHi, actLo, at2s, at2d, asQ, adQ);

    // ---- Layer 2 (fused skip: B = [W2; Wskip], M=2800; skip cols 1-product) ----
    {
        int M = 2800;
        dim3 grid((M + 255) / 256, gy);
        gemm_hilo2<<<grid, blk, 0, stream>>>(actHi, actLo, w2Hi, hpreb, NNODES, M, KP2,
                                             2800, 1408);
        // agg reads alpha2 (Q), writes act2 + alpha3 (P)
        agg2<NH2, HIDC, 0, 1, 1, 6><<<NNODES, AGG_T, 0, stream>>>(
            hpreb, 2800, asQ, adQ, indptr, esrc, b2, actHi, actLo, KP2, nullptr,
            at3s, at3d, asP, adP);
    }
    // ---- Layer 3 (2-product everywhere) ----
    {
        int M = NH3 * OUTC;  // 726
        dim3 grid((M + 255) / 256, gy);
        gemm_hilo2<<<grid, blk, 0, stream>>>(actHi, actLo, w3Hi, hpreb, NNODES, M, KP2,
                                             LD3, KP2);
        agg2<NH3, OUTC, 1, 0, 0, 0><<<NNODES, AGG_T, 0, stream>>>(
            hpreb, LD3, asP, adP, indptr, esrc, b3, nullptr, nullptr, 0, out,
            nullptr, nullptr, nullptr, nullptr);
    }
}